// Round 4
// baseline (1125.016 us; speedup 1.0000x reference)
//
#include <hip/hip_runtime.h>
#include <hip/hip_bf16.h>

#define EPS   1e-5f
#define NH    4      // heads
#define DIN   128
#define DHID  64
#define DOUT  32
#define ROWS  8      // nodes per GEMM block

__device__ __forceinline__ float b2f(__hip_bfloat16 v) { return __bfloat162float(v); }

// monotonic float<->int mapping for atomicMax on floats
__device__ __forceinline__ int f2ord(float f) {
    int i = __float_as_int(f);
    return (i >= 0) ? i : (i ^ 0x7fffffff);
}
__device__ __forceinline__ float ord2f(int o) {
    return (o >= 0) ? __int_as_float(o) : __int_as_float(o ^ 0x7fffffff);
}

// ---------------------------------------------------------------- init
// zeroes mi/ssum (N*4), outacc (N*64), pool+cnt (G*64+G, contiguous)
__global__ void k_init(int* __restrict__ mi, float* __restrict__ ssum,
                       float* __restrict__ outacc, float* __restrict__ pool,
                       int n4, int n64, int npool) {
    int g = blockIdx.x * blockDim.x + threadIdx.x;
    if (g < n4) { mi[g] = (int)0x80000000; ssum[g] = 0.f; }
    if (g < n64) outacc[g] = 0.f;
    if (g < npool) pool[g] = 0.f;
}

// ---------------------------------------------------------------- layer-1 GEMM
// fused: input BatchNorm -> h1 = xn @ W1 [N,256] (stored bf16); a_src/a_dst from f32 acc
__global__ __launch_bounds__(256) void k_gemm1(
    const float* __restrict__ x,
    const float* __restrict__ ing, const float* __restrict__ inb,
    const float* __restrict__ inm, const float* __restrict__ inv,
    const float* __restrict__ W,      // [128,256]
    const float* __restrict__ as_, const float* __restrict__ ad_, // [256]
    __hip_bfloat16* __restrict__ h, float* __restrict__ asrc, float* __restrict__ adst, int N)
{
    __shared__ float xs[ROWS][DIN];
    const int t = threadIdx.x;
    const int base = blockIdx.x * ROWS;

    #pragma unroll
    for (int j = 0; j < ROWS * DIN / 256; ++j) {
        int idx = t + j * 256;
        int r = idx >> 7, k = idx & 127;
        int node = base + r;
        float val = 0.f;
        if (node < N) {
            float xv = x[(size_t)node * DIN + k];
            val = (xv - inm[k]) * rsqrtf(inv[k] + EPS) * ing[k] + inb[k];
        }
        xs[r][k] = val;
    }
    __syncthreads();

    float acc[ROWS];
    #pragma unroll
    for (int r = 0; r < ROWS; ++r) acc[r] = 0.f;
    for (int k = 0; k < DIN; ++k) {
        float w = W[k * 256 + t];
        #pragma unroll
        for (int r = 0; r < ROWS; ++r) acc[r] += xs[r][k] * w;
    }

    const float asv = as_[t], adv = ad_[t];
    const int head = t >> 6, lane = t & 63;
    for (int r = 0; r < ROWS; ++r) {
        int node = base + r;
        if (node >= N) break;                 // uniform across block
        h[(size_t)node * 256 + t] = __float2bfloat16(acc[r]);
        float vs = acc[r] * asv, vd = acc[r] * adv;
        #pragma unroll
        for (int o = 32; o > 0; o >>= 1) {
            vs += __shfl_down(vs, o, 64);
            vd += __shfl_down(vd, o, 64);
        }
        if (lane == 0) {
            asrc[node * NH + head] = vs;
            adst[node * NH + head] = vd;
        }
    }
}

// ---------------------------------------------------------------- layer-2 GEMM
// fused: (+b1, BN1, ReLU) epilogue on layer-1 aggregate -> h3 = h2 @ W2 (stored bf16)
__global__ __launch_bounds__(256) void k_gemm2(
    const float* __restrict__ outacc,
    const float* __restrict__ b1,
    const float* __restrict__ bg, const float* __restrict__ bb,
    const float* __restrict__ bm, const float* __restrict__ bv,
    const float* __restrict__ W,      // [64,256]
    const float* __restrict__ as_, const float* __restrict__ ad_,
    __hip_bfloat16* __restrict__ h, float* __restrict__ asrc, float* __restrict__ adst, int N)
{
    __shared__ float xs[ROWS][DHID];
    const int t = threadIdx.x;
    const int base = blockIdx.x * ROWS;

    #pragma unroll
    for (int j = 0; j < ROWS * DHID / 256; ++j) {
        int idx = t + j * 256;
        int r = idx >> 6, c = idx & 63;
        int node = base + r;
        float val = 0.f;
        if (node < N) {
            float raw = outacc[(size_t)node * DHID + c] + b1[c];
            float bnv = (raw - bm[c]) * rsqrtf(bv[c] + EPS) * bg[c] + bb[c];
            val = fmaxf(bnv, 0.f);
        }
        xs[r][c] = val;
    }
    __syncthreads();

    float acc[ROWS];
    #pragma unroll
    for (int r = 0; r < ROWS; ++r) acc[r] = 0.f;
    for (int k = 0; k < DHID; ++k) {
        float w = W[k * 256 + t];
        #pragma unroll
        for (int r = 0; r < ROWS; ++r) acc[r] += xs[r][k] * w;
    }

    const float asv = as_[t], adv = ad_[t];
    const int head = t >> 6, lane = t & 63;
    for (int r = 0; r < ROWS; ++r) {
        int node = base + r;
        if (node >= N) break;
        h[(size_t)node * 256 + t] = __float2bfloat16(acc[r]);
        float vs = acc[r] * asv, vd = acc[r] * adv;
        #pragma unroll
        for (int o = 32; o > 0; o >>= 1) {
            vs += __shfl_down(vs, o, 64);
            vd += __shfl_down(vd, o, 64);
        }
        if (lane == 0) {
            asrc[node * NH + head] = vs;
            adst[node * NH + head] = vd;
        }
    }
}

// ---------------------------------------------------------------- edge pass A: segment max
__global__ void k_edge_max(const int* __restrict__ ei, int E, int N,
                           const float* __restrict__ asrc, const float* __restrict__ adst,
                           int* __restrict__ mi)
{
    int g = blockIdx.x * blockDim.x + threadIdx.x;
    int tot = (E + N) * NH;
    if (g >= tot) return;
    int e = g >> 2, hh = g & 3;
    int s, d;
    if (e < E) { s = ei[e]; d = ei[E + e]; } else { s = d = e - E; }
    float a = asrc[s * NH + hh] + adst[d * NH + hh];
    float lr = (a >= 0.f) ? a : 0.2f * a;
    atomicMax(&mi[d * NH + hh], f2ord(lr));
}

// ---------------------------------------------------------------- edge pass B: exp + segment sum
__global__ void k_edge_sum(const int* __restrict__ ei, int E, int N,
                           const float* __restrict__ asrc, const float* __restrict__ adst,
                           const int* __restrict__ mi, float* __restrict__ ssum)
{
    int g = blockIdx.x * blockDim.x + threadIdx.x;
    int tot = (E + N) * NH;
    if (g >= tot) return;
    int e = g >> 2, hh = g & 3;
    int s, d;
    if (e < E) { s = ei[e]; d = ei[E + e]; } else { s = d = e - E; }
    float a = asrc[s * NH + hh] + adst[d * NH + hh];
    float lr = (a >= 0.f) ? a : 0.2f * a;
    float m = ord2f(mi[d * NH + hh]);
    atomicAdd(&ssum[d * NH + hh], __expf(lr - m));
}

// ---------------------------------------------------------------- edge pass C: aggregate
// one wave (64 lanes = 64 channels) per edge; heads folded with mean; alpha recomputed
__global__ __launch_bounds__(256) void k_edge_agg(
    const int* __restrict__ ei, int E, int N,
    const float* __restrict__ asrc, const float* __restrict__ adst,
    const int* __restrict__ mi, const float* __restrict__ ssum,
    const __hip_bfloat16* __restrict__ h, float* __restrict__ outacc)
{
    int g = blockIdx.x * blockDim.x + threadIdx.x;
    int e = g >> 6;
    int lane = g & 63;
    int tot = E + N;
    if (e >= tot) return;
    int s, d;
    if (e < E) { s = ei[e]; d = ei[E + e]; } else { s = d = e - E; }
    float w[NH];
    #pragma unroll
    for (int hh = 0; hh < NH; ++hh) {
        float a = asrc[s * NH + hh] + adst[d * NH + hh];
        float lr = (a >= 0.f) ? a : 0.2f * a;
        float m = ord2f(mi[d * NH + hh]);
        w[hh] = __expf(lr - m) / ssum[d * NH + hh];
    }
    const __hip_bfloat16* hs = h + (size_t)s * 256;
    float val = 0.25f * (w[0] * b2f(hs[lane]) + w[1] * b2f(hs[64 + lane]) +
                         w[2] * b2f(hs[128 + lane]) + w[3] * b2f(hs[192 + lane]));
    atomicAdd(&outacc[(size_t)d * 64 + lane], val);
}

// ---------------------------------------------------------------- pool: bias+BN2+ReLU, mean-pool accum
__global__ void k_pool(const float* __restrict__ outacc,
                       const float* __restrict__ b2_,
                       const float* __restrict__ bg, const float* __restrict__ bb,
                       const float* __restrict__ bm, const float* __restrict__ bv,
                       const int* __restrict__ batch,
                       float* __restrict__ pool, float* __restrict__ cnt, int N)
{
    int g = blockIdx.x * blockDim.x + threadIdx.x;
    if (g >= N * 64) return;
    int n = g >> 6, c = g & 63;
    float raw = outacc[g] + b2_[c];
    float bnv = (raw - bm[c]) * rsqrtf(bv[c] + EPS) * bg[c] + bb[c];
    float v = fmaxf(bnv, 0.f);
    int gr = batch[n];
    atomicAdd(&pool[gr * 64 + c], v);
    if (c == 0) atomicAdd(&cnt[gr], 1.0f);
}

// ---------------------------------------------------------------- head: emb -> fc1(relu) -> fc2
__global__ void k_head(const float* __restrict__ pool, const float* __restrict__ cnt,
                       const float* __restrict__ fc1w, const float* __restrict__ fc1b,
                       const float* __restrict__ fc2w, const float* __restrict__ fc2b,
                       float* __restrict__ out)
{
    int g = blockIdx.x;
    int t = threadIdx.x;  // 64 threads
    __shared__ float emb[64];
    __shared__ float z1[32];
    float c = fmaxf(cnt[g], 1.0f);
    emb[t] = pool[g * 64 + t] / c;
    __syncthreads();
    if (t < 32) {
        float s = fc1b[t];
        for (int k = 0; k < 64; ++k) s += emb[k] * fc1w[k * 32 + t];
        z1[t] = fmaxf(s, 0.f);
    }
    __syncthreads();
    if (t < 32) {
        float o = fc2b[t];
        for (int j = 0; j < 32; ++j) o += z1[j] * fc2w[j * 32 + t];
        out[g * 32 + t] = o;
    }
}

// ---------------------------------------------------------------- launch
extern "C" void kernel_launch(void* const* d_in, const int* in_sizes, int n_in,
                              void* d_out, int out_size, void* d_ws, size_t ws_size,
                              hipStream_t stream)
{
    const float* x    = (const float*)d_in[0];
    const int*   ei   = (const int*)d_in[1];
    const int*   batch= (const int*)d_in[2];
    const float* ing  = (const float*)d_in[3];
    const float* inb  = (const float*)d_in[4];
    const float* inm  = (const float*)d_in[5];
    const float* inv  = (const float*)d_in[6];
    const float* W1   = (const float*)d_in[7];
    const float* as1  = (const float*)d_in[8];
    const float* ad1  = (const float*)d_in[9];
    const float* b1   = (const float*)d_in[10];
    const float* bn1g = (const float*)d_in[11];
    const float* bn1b = (const float*)d_in[12];
    const float* bn1m = (const float*)d_in[13];
    const float* bn1v = (const float*)d_in[14];
    const float* W2   = (const float*)d_in[15];
    const float* as2  = (const float*)d_in[16];
    const float* ad2  = (const float*)d_in[17];
    const float* b2   = (const float*)d_in[18];
    const float* bn2g = (const float*)d_in[19];
    const float* bn2b = (const float*)d_in[20];
    const float* bn2m = (const float*)d_in[21];
    const float* bn2v = (const float*)d_in[22];
    const float* fc1w = (const float*)d_in[23];
    const float* fc1b = (const float*)d_in[24];
    const float* fc2w = (const float*)d_in[25];
    const float* fc2b = (const float*)d_in[26];

    const int N = in_sizes[0] / DIN;
    const int E = in_sizes[1] / 2;
    const int G = out_size / DOUT;
    const int Etot = E + N;

    // workspace layout — total ~42 MB (h bf16)
    __hip_bfloat16* h = (__hip_bfloat16*)d_ws;            // N*256 bf16
    float* asrc   = (float*)(h + (size_t)N * 256);        // N*4
    float* adst   = asrc + (size_t)N * NH;                // N*4
    int*   mi     = (int*)(adst + (size_t)N * NH);        // N*4
    float* ssum   = (float*)(mi + (size_t)N * NH);        // N*4
    float* outacc = ssum + (size_t)N * NH;                // N*64
    float* pool   = outacc + (size_t)N * DHID;            // G*64
    float* cnt    = pool + (size_t)G * DHID;              // G (contiguous with pool)

    const int n4 = N * NH, n64 = N * DHID, npool = G * DHID + G;
    dim3 b256(256);
    const int gInit = (n64 + 255) / 256;
    const int gEdge = (Etot * NH + 255) / 256;
    const int gAgg  = (int)(((size_t)Etot * 64 + 255) / 256);

    // ---- layer 1
    k_init<<<gInit, b256, 0, stream>>>(mi, ssum, outacc, pool, n4, n64, npool);
    k_gemm1<<<(N + ROWS - 1) / ROWS, b256, 0, stream>>>(x, ing, inb, inm, inv, W1, as1, ad1,
                                                        h, asrc, adst, N);
    k_edge_max<<<gEdge, b256, 0, stream>>>(ei, E, N, asrc, adst, mi);
    k_edge_sum<<<gEdge, b256, 0, stream>>>(ei, E, N, asrc, adst, mi, ssum);
    k_edge_agg<<<gAgg, b256, 0, stream>>>(ei, E, N, asrc, adst, mi, ssum, h, outacc);

    // ---- layer 2 (gemm2 consumes outacc before re-init)
    k_gemm2<<<(N + ROWS - 1) / ROWS, b256, 0, stream>>>(outacc, b1, bn1g, bn1b, bn1m, bn1v,
                                                        W2, as2, ad2, h, asrc, adst, N);
    k_init<<<gInit, b256, 0, stream>>>(mi, ssum, outacc, pool, n4, n64, npool);
    k_edge_max<<<gEdge, b256, 0, stream>>>(ei, E, N, asrc, adst, mi);
    k_edge_sum<<<gEdge, b256, 0, stream>>>(ei, E, N, asrc, adst, mi, ssum);
    k_edge_agg<<<gAgg, b256, 0, stream>>>(ei, E, N, asrc, adst, mi, ssum, h, outacc);

    // ---- pool + head
    k_pool<<<gInit, b256, 0, stream>>>(outacc, b2, bn2g, bn2b, bn2m, bn2v, batch, pool, cnt, N);
    k_head<<<G, 64, 0, stream>>>(pool, cnt, fc1w, fc1b, fc2w, fc2b, (float*)d_out);
}

// Round 5
// 884.744 us; speedup vs baseline: 1.2716x; 1.2716x over previous
//
#include <hip/hip_runtime.h>
#include <hip/hip_bf16.h>

#define EPS   1e-5f
#define NH    4      // heads
#define DIN   128
#define DHID  64
#define DOUT  32
#define ROWS  8      // nodes per GEMM block
#define PNODES 256   // nodes per k_pool block (batch sorted -> few graph-runs per block)

__device__ __forceinline__ float b2f(__hip_bfloat16 v) { return __bfloat162float(v); }

// monotonic float<->int mapping for atomicMax on floats
__device__ __forceinline__ int f2ord(float f) {
    int i = __float_as_int(f);
    return (i >= 0) ? i : (i ^ 0x7fffffff);
}
__device__ __forceinline__ float ord2f(int o) {
    return (o >= 0) ? __int_as_float(o) : __int_as_float(o ^ 0x7fffffff);
}

// ---------------------------------------------------------------- init
// zeroes mi/ssum (N*4), outacc (N*64), pool+cnt (G*64+G, contiguous)
__global__ void k_init(int* __restrict__ mi, float* __restrict__ ssum,
                       float* __restrict__ outacc, float* __restrict__ pool,
                       int n4, int n64, int npool) {
    int g = blockIdx.x * blockDim.x + threadIdx.x;
    if (g < n4) { mi[g] = (int)0x80000000; ssum[g] = 0.f; }
    if (g < n64) outacc[g] = 0.f;
    if (g < npool) pool[g] = 0.f;
}

// ---------------------------------------------------------------- layer-1 GEMM
// fused: input BatchNorm -> h1 = xn @ W1 [N,256] (stored bf16); a_src/a_dst from f32 acc
__global__ __launch_bounds__(256) void k_gemm1(
    const float* __restrict__ x,
    const float* __restrict__ ing, const float* __restrict__ inb,
    const float* __restrict__ inm, const float* __restrict__ inv,
    const float* __restrict__ W,      // [128,256]
    const float* __restrict__ as_, const float* __restrict__ ad_, // [256]
    __hip_bfloat16* __restrict__ h, float* __restrict__ asrc, float* __restrict__ adst, int N)
{
    __shared__ float xs[ROWS][DIN];
    const int t = threadIdx.x;
    const int base = blockIdx.x * ROWS;

    #pragma unroll
    for (int j = 0; j < ROWS * DIN / 256; ++j) {
        int idx = t + j * 256;
        int r = idx >> 7, k = idx & 127;
        int node = base + r;
        float val = 0.f;
        if (node < N) {
            float xv = x[(size_t)node * DIN + k];
            val = (xv - inm[k]) * rsqrtf(inv[k] + EPS) * ing[k] + inb[k];
        }
        xs[r][k] = val;
    }
    __syncthreads();

    float acc[ROWS];
    #pragma unroll
    for (int r = 0; r < ROWS; ++r) acc[r] = 0.f;
    for (int k = 0; k < DIN; ++k) {
        float w = W[k * 256 + t];
        #pragma unroll
        for (int r = 0; r < ROWS; ++r) acc[r] += xs[r][k] * w;
    }

    const float asv = as_[t], adv = ad_[t];
    const int head = t >> 6, lane = t & 63;
    for (int r = 0; r < ROWS; ++r) {
        int node = base + r;
        if (node >= N) break;                 // uniform across block
        h[(size_t)node * 256 + t] = __float2bfloat16(acc[r]);
        float vs = acc[r] * asv, vd = acc[r] * adv;
        #pragma unroll
        for (int o = 32; o > 0; o >>= 1) {
            vs += __shfl_down(vs, o, 64);
            vd += __shfl_down(vd, o, 64);
        }
        if (lane == 0) {
            asrc[node * NH + head] = vs;
            adst[node * NH + head] = vd;
        }
    }
}

// ---------------------------------------------------------------- layer-2 GEMM
// fused: (+b1, BN1, ReLU) epilogue on layer-1 aggregate -> h3 = h2 @ W2 (stored bf16)
__global__ __launch_bounds__(256) void k_gemm2(
    const float* __restrict__ outacc,
    const float* __restrict__ b1,
    const float* __restrict__ bg, const float* __restrict__ bb,
    const float* __restrict__ bm, const float* __restrict__ bv,
    const float* __restrict__ W,      // [64,256]
    const float* __restrict__ as_, const float* __restrict__ ad_,
    __hip_bfloat16* __restrict__ h, float* __restrict__ asrc, float* __restrict__ adst, int N)
{
    __shared__ float xs[ROWS][DHID];
    const int t = threadIdx.x;
    const int base = blockIdx.x * ROWS;

    #pragma unroll
    for (int j = 0; j < ROWS * DHID / 256; ++j) {
        int idx = t + j * 256;
        int r = idx >> 6, c = idx & 63;
        int node = base + r;
        float val = 0.f;
        if (node < N) {
            float raw = outacc[(size_t)node * DHID + c] + b1[c];
            float bnv = (raw - bm[c]) * rsqrtf(bv[c] + EPS) * bg[c] + bb[c];
            val = fmaxf(bnv, 0.f);
        }
        xs[r][c] = val;
    }
    __syncthreads();

    float acc[ROWS];
    #pragma unroll
    for (int r = 0; r < ROWS; ++r) acc[r] = 0.f;
    for (int k = 0; k < DHID; ++k) {
        float w = W[k * 256 + t];
        #pragma unroll
        for (int r = 0; r < ROWS; ++r) acc[r] += xs[r][k] * w;
    }

    const float asv = as_[t], adv = ad_[t];
    const int head = t >> 6, lane = t & 63;
    for (int r = 0; r < ROWS; ++r) {
        int node = base + r;
        if (node >= N) break;
        h[(size_t)node * 256 + t] = __float2bfloat16(acc[r]);
        float vs = acc[r] * asv, vd = acc[r] * adv;
        #pragma unroll
        for (int o = 32; o > 0; o >>= 1) {
            vs += __shfl_down(vs, o, 64);
            vd += __shfl_down(vd, o, 64);
        }
        if (lane == 0) {
            asrc[node * NH + head] = vs;
            adst[node * NH + head] = vd;
        }
    }
}

// ---------------------------------------------------------------- edge pass A: segment max
__global__ void k_edge_max(const int* __restrict__ ei, int E, int N,
                           const float* __restrict__ asrc, const float* __restrict__ adst,
                           int* __restrict__ mi)
{
    int g = blockIdx.x * blockDim.x + threadIdx.x;
    int tot = (E + N) * NH;
    if (g >= tot) return;
    int e = g >> 2, hh = g & 3;
    int s, d;
    if (e < E) { s = ei[e]; d = ei[E + e]; } else { s = d = e - E; }
    float a = asrc[s * NH + hh] + adst[d * NH + hh];
    float lr = (a >= 0.f) ? a : 0.2f * a;
    atomicMax(&mi[d * NH + hh], f2ord(lr));
}

// ---------------------------------------------------------------- edge pass B: exp + segment sum
__global__ void k_edge_sum(const int* __restrict__ ei, int E, int N,
                           const float* __restrict__ asrc, const float* __restrict__ adst,
                           const int* __restrict__ mi, float* __restrict__ ssum)
{
    int g = blockIdx.x * blockDim.x + threadIdx.x;
    int tot = (E + N) * NH;
    if (g >= tot) return;
    int e = g >> 2, hh = g & 3;
    int s, d;
    if (e < E) { s = ei[e]; d = ei[E + e]; } else { s = d = e - E; }
    float a = asrc[s * NH + hh] + adst[d * NH + hh];
    float lr = (a >= 0.f) ? a : 0.2f * a;
    float m = ord2f(mi[d * NH + hh]);
    atomicAdd(&ssum[d * NH + hh], __expf(lr - m));
}

// ---------------------------------------------------------------- edge pass C: aggregate
// one wave (64 lanes = 64 channels) per edge; heads folded with mean; alpha recomputed
__global__ __launch_bounds__(256) void k_edge_agg(
    const int* __restrict__ ei, int E, int N,
    const float* __restrict__ asrc, const float* __restrict__ adst,
    const int* __restrict__ mi, const float* __restrict__ ssum,
    const __hip_bfloat16* __restrict__ h, float* __restrict__ outacc)
{
    int g = blockIdx.x * blockDim.x + threadIdx.x;
    int e = g >> 6;
    int lane = g & 63;
    int tot = E + N;
    if (e >= tot) return;
    int s, d;
    if (e < E) { s = ei[e]; d = ei[E + e]; } else { s = d = e - E; }
    float w[NH];
    #pragma unroll
    for (int hh = 0; hh < NH; ++hh) {
        float a = asrc[s * NH + hh] + adst[d * NH + hh];
        float lr = (a >= 0.f) ? a : 0.2f * a;
        float m = ord2f(mi[d * NH + hh]);
        w[hh] = __expf(lr - m) / ssum[d * NH + hh];
    }
    const __hip_bfloat16* hs = h + (size_t)s * 256;
    float val = 0.25f * (w[0] * b2f(hs[lane]) + w[1] * b2f(hs[64 + lane]) +
                         w[2] * b2f(hs[128 + lane]) + w[3] * b2f(hs[192 + lane]));
    atomicAdd(&outacc[(size_t)d * 64 + lane], val);
}

// ---------------------------------------------------------------- pool (REWRITTEN)
// batch is SORTED. One wave per node-stream: lane = channel, wave walks nodes
// base+wave, base+wave+4, ...; accumulate per-graph run in registers, flush one
// atomicAdd per (run, channel) on graph change (wave-uniform branch).
__global__ __launch_bounds__(256) void k_pool(
    const float* __restrict__ outacc,
    const float* __restrict__ b2_,
    const float* __restrict__ bg, const float* __restrict__ bb,
    const float* __restrict__ bm, const float* __restrict__ bv,
    const int* __restrict__ batch,
    float* __restrict__ pool, float* __restrict__ cnt, int N)
{
    const int lane = threadIdx.x & 63;
    const int wave = threadIdx.x >> 6;           // 0..3
    const int base = blockIdx.x * PNODES;
    int end = base + PNODES; if (end > N) end = N;

    // hoisted BN constants: v = relu(outacc*scale + shift)
    const float scale = bg[lane] * rsqrtf(bv[lane] + EPS);
    const float shift = (b2_[lane] - bm[lane]) * scale + bb[lane];

    float acc = 0.f;
    int cur = -1, cl = 0;
    for (int n = base + wave; n < end; n += 4) {
        int gr = batch[n];                       // wave-uniform
        if (gr != cur) {
            if (cur >= 0) {
                atomicAdd(&pool[cur * 64 + lane], acc);
                if (lane == 0) atomicAdd(&cnt[cur], (float)cl);
            }
            cur = gr; acc = 0.f; cl = 0;
        }
        float v = fmaxf(outacc[(size_t)n * 64 + lane] * scale + shift, 0.f);
        acc += v; ++cl;
    }
    if (cur >= 0) {
        atomicAdd(&pool[cur * 64 + lane], acc);
        if (lane == 0) atomicAdd(&cnt[cur], (float)cl);
    }
}

// ---------------------------------------------------------------- head: emb -> fc1(relu) -> fc2
__global__ void k_head(const float* __restrict__ pool, const float* __restrict__ cnt,
                       const float* __restrict__ fc1w, const float* __restrict__ fc1b,
                       const float* __restrict__ fc2w, const float* __restrict__ fc2b,
                       float* __restrict__ out)
{
    int g = blockIdx.x;
    int t = threadIdx.x;  // 64 threads
    __shared__ float emb[64];
    __shared__ float z1[32];
    float c = fmaxf(cnt[g], 1.0f);
    emb[t] = pool[g * 64 + t] / c;
    __syncthreads();
    if (t < 32) {
        float s = fc1b[t];
        for (int k = 0; k < 64; ++k) s += emb[k] * fc1w[k * 32 + t];
        z1[t] = fmaxf(s, 0.f);
    }
    __syncthreads();
    if (t < 32) {
        float o = fc2b[t];
        for (int j = 0; j < 32; ++j) o += z1[j] * fc2w[j * 32 + t];
        out[g * 32 + t] = o;
    }
}

// ---------------------------------------------------------------- launch
extern "C" void kernel_launch(void* const* d_in, const int* in_sizes, int n_in,
                              void* d_out, int out_size, void* d_ws, size_t ws_size,
                              hipStream_t stream)
{
    const float* x    = (const float*)d_in[0];
    const int*   ei   = (const int*)d_in[1];
    const int*   batch= (const int*)d_in[2];
    const float* ing  = (const float*)d_in[3];
    const float* inb  = (const float*)d_in[4];
    const float* inm  = (const float*)d_in[5];
    const float* inv  = (const float*)d_in[6];
    const float* W1   = (const float*)d_in[7];
    const float* as1  = (const float*)d_in[8];
    const float* ad1  = (const float*)d_in[9];
    const float* b1   = (const float*)d_in[10];
    const float* bn1g = (const float*)d_in[11];
    const float* bn1b = (const float*)d_in[12];
    const float* bn1m = (const float*)d_in[13];
    const float* bn1v = (const float*)d_in[14];
    const float* W2   = (const float*)d_in[15];
    const float* as2  = (const float*)d_in[16];
    const float* ad2  = (const float*)d_in[17];
    const float* b2   = (const float*)d_in[18];
    const float* bn2g = (const float*)d_in[19];
    const float* bn2b = (const float*)d_in[20];
    const float* bn2m = (const float*)d_in[21];
    const float* bn2v = (const float*)d_in[22];
    const float* fc1w = (const float*)d_in[23];
    const float* fc1b = (const float*)d_in[24];
    const float* fc2w = (const float*)d_in[25];
    const float* fc2b = (const float*)d_in[26];

    const int N = in_sizes[0] / DIN;
    const int E = in_sizes[1] / 2;
    const int G = out_size / DOUT;
    const int Etot = E + N;

    // workspace layout — total ~42 MB (h bf16)
    __hip_bfloat16* h = (__hip_bfloat16*)d_ws;            // N*256 bf16
    float* asrc   = (float*)(h + (size_t)N * 256);        // N*4
    float* adst   = asrc + (size_t)N * NH;                // N*4
    int*   mi     = (int*)(adst + (size_t)N * NH);        // N*4
    float* ssum   = (float*)(mi + (size_t)N * NH);        // N*4
    float* outacc = ssum + (size_t)N * NH;                // N*64
    float* pool   = outacc + (size_t)N * DHID;            // G*64
    float* cnt    = pool + (size_t)G * DHID;              // G (contiguous with pool)

    const int n4 = N * NH, n64 = N * DHID, npool = G * DHID + G;
    dim3 b256(256);
    const int gInit = (n64 + 255) / 256;
    const int gEdge = (Etot * NH + 255) / 256;
    const int gAgg  = (int)(((size_t)Etot * 64 + 255) / 256);

    // ---- layer 1
    k_init<<<gInit, b256, 0, stream>>>(mi, ssum, outacc, pool, n4, n64, npool);
    k_gemm1<<<(N + ROWS - 1) / ROWS, b256, 0, stream>>>(x, ing, inb, inm, inv, W1, as1, ad1,
                                                        h, asrc, adst, N);
    k_edge_max<<<gEdge, b256, 0, stream>>>(ei, E, N, asrc, adst, mi);
    k_edge_sum<<<gEdge, b256, 0, stream>>>(ei, E, N, asrc, adst, mi, ssum);
    k_edge_agg<<<gAgg, b256, 0, stream>>>(ei, E, N, asrc, adst, mi, ssum, h, outacc);

    // ---- layer 2 (gemm2 consumes outacc before re-init)
    k_gemm2<<<(N + ROWS - 1) / ROWS, b256, 0, stream>>>(outacc, b1, bn1g, bn1b, bn1m, bn1v,
                                                        W2, as2, ad2, h, asrc, adst, N);
    k_init<<<gInit, b256, 0, stream>>>(mi, ssum, outacc, pool, n4, n64, npool);
    k_edge_max<<<gEdge, b256, 0, stream>>>(ei, E, N, asrc, adst, mi);
    k_edge_sum<<<gEdge, b256, 0, stream>>>(ei, E, N, asrc, adst, mi, ssum);
    k_edge_agg<<<gAgg, b256, 0, stream>>>(ei, E, N, asrc, adst, mi, ssum, h, outacc);

    // ---- pool + head
    k_pool<<<(N + PNODES - 1) / PNODES, b256, 0, stream>>>(outacc, b2, bn2g, bn2b, bn2m, bn2v,
                                                           batch, pool, cnt, N);
    k_head<<<G, 64, 0, stream>>>(pool, cnt, fc1w, fc1b, fc2w, fc2b, (float*)d_out);
}

// Round 6
// 689.773 us; speedup vs baseline: 1.6310x; 1.2827x over previous
//
#include <hip/hip_runtime.h>
#include <hip/hip_bf16.h>

#define EPS   1e-5f
#define NH    4      // heads
#define DIN   128
#define DHID  64
#define DOUT  32
#define ROWS  8      // nodes per GEMM block
#define PNODES 256   // nodes per k_pool block
#define CAP   128    // per-wave LDS edge capacity in k_agg (deg ~Poisson(17); >128 ~never)

__device__ __forceinline__ float b2f(__hip_bfloat16 v) { return __bfloat162float(v); }

// ---------------------------------------------------------------- init: deg=1 (self-loop), zero pool/cnt
__global__ void k_init0(int* __restrict__ deg, float* __restrict__ pool, int N, int npool) {
    int g = blockIdx.x * blockDim.x + threadIdx.x;
    if (g < N) deg[g] = 1;
    if (g < npool) pool[g] = 0.f;
}

// ---------------------------------------------------------------- CSR build: histogram of dst
__global__ void k_hist(const int* __restrict__ ei, int* __restrict__ deg, int E) {
    int e = blockIdx.x * blockDim.x + threadIdx.x;
    if (e < E) atomicAdd(&deg[ei[E + e]], 1);
}

// ---------------------------------------------------------------- CSR build: exclusive scan (1 block, 1024 thr)
__global__ __launch_bounds__(1024) void k_scan(const int* __restrict__ deg,
                                               int* __restrict__ rowptr, int* __restrict__ cursor, int N) {
    __shared__ int part[1024];
    const int t = threadIdx.x;
    const int C = (N + 1023) / 1024;
    const int b0 = t * C;
    const int b1 = (b0 + C < N) ? b0 + C : N;
    int s = 0;
    for (int i = b0; i < b1; ++i) s += deg[i];
    part[t] = s;
    __syncthreads();
    // Hillis-Steele inclusive scan
    for (int o = 1; o < 1024; o <<= 1) {
        int v = (t >= o) ? part[t - o] : 0;
        __syncthreads();
        part[t] += v;
        __syncthreads();
    }
    int run = (t == 0) ? 0 : part[t - 1];
    for (int i = b0; i < b1; ++i) { int v = deg[i]; rowptr[i] = run; cursor[i] = run; run += v; }
    if (t == 1023) rowptr[N] = part[1023];
}

// ---------------------------------------------------------------- CSR build: scatter src ids (+self-loops)
__global__ void k_fill(const int* __restrict__ ei, int* __restrict__ cursor,
                       int* __restrict__ col, int E, int N) {
    int g = blockIdx.x * blockDim.x + threadIdx.x;
    if (g >= E + N) return;
    int s, d;
    if (g < E) { s = ei[g]; d = ei[E + g]; } else { s = d = g - E; }
    int pos = atomicAdd(&cursor[d], 1);
    col[pos] = s;
}

// ---------------------------------------------------------------- layer-1 GEMM (unchanged)
__global__ __launch_bounds__(256) void k_gemm1(
    const float* __restrict__ x,
    const float* __restrict__ ing, const float* __restrict__ inb,
    const float* __restrict__ inm, const float* __restrict__ inv,
    const float* __restrict__ W,      // [128,256]
    const float* __restrict__ as_, const float* __restrict__ ad_, // [256]
    __hip_bfloat16* __restrict__ h, float* __restrict__ asrc, float* __restrict__ adst, int N)
{
    __shared__ float xs[ROWS][DIN];
    const int t = threadIdx.x;
    const int base = blockIdx.x * ROWS;

    #pragma unroll
    for (int j = 0; j < ROWS * DIN / 256; ++j) {
        int idx = t + j * 256;
        int r = idx >> 7, k = idx & 127;
        int node = base + r;
        float val = 0.f;
        if (node < N) {
            float xv = x[(size_t)node * DIN + k];
            val = (xv - inm[k]) * rsqrtf(inv[k] + EPS) * ing[k] + inb[k];
        }
        xs[r][k] = val;
    }
    __syncthreads();

    float acc[ROWS];
    #pragma unroll
    for (int r = 0; r < ROWS; ++r) acc[r] = 0.f;
    for (int k = 0; k < DIN; ++k) {
        float w = W[k * 256 + t];
        #pragma unroll
        for (int r = 0; r < ROWS; ++r) acc[r] += xs[r][k] * w;
    }

    const float asv = as_[t], adv = ad_[t];
    const int head = t >> 6, lane = t & 63;
    for (int r = 0; r < ROWS; ++r) {
        int node = base + r;
        if (node >= N) break;
        h[(size_t)node * 256 + t] = __float2bfloat16(acc[r]);
        float vs = acc[r] * asv, vd = acc[r] * adv;
        #pragma unroll
        for (int o = 32; o > 0; o >>= 1) {
            vs += __shfl_down(vs, o, 64);
            vd += __shfl_down(vd, o, 64);
        }
        if (lane == 0) {
            asrc[node * NH + head] = vs;
            adst[node * NH + head] = vd;
        }
    }
}

// ---------------------------------------------------------------- layer-2 GEMM (unchanged)
__global__ __launch_bounds__(256) void k_gemm2(
    const float* __restrict__ outacc,
    const float* __restrict__ b1,
    const float* __restrict__ bg, const float* __restrict__ bb,
    const float* __restrict__ bm, const float* __restrict__ bv,
    const float* __restrict__ W,      // [64,256]
    const float* __restrict__ as_, const float* __restrict__ ad_,
    __hip_bfloat16* __restrict__ h, float* __restrict__ asrc, float* __restrict__ adst, int N)
{
    __shared__ float xs[ROWS][DHID];
    const int t = threadIdx.x;
    const int base = blockIdx.x * ROWS;

    #pragma unroll
    for (int j = 0; j < ROWS * DHID / 256; ++j) {
        int idx = t + j * 256;
        int r = idx >> 6, c = idx & 63;
        int node = base + r;
        float val = 0.f;
        if (node < N) {
            float raw = outacc[(size_t)node * DHID + c] + b1[c];
            float bnv = (raw - bm[c]) * rsqrtf(bv[c] + EPS) * bg[c] + bb[c];
            val = fmaxf(bnv, 0.f);
        }
        xs[r][c] = val;
    }
    __syncthreads();

    float acc[ROWS];
    #pragma unroll
    for (int r = 0; r < ROWS; ++r) acc[r] = 0.f;
    for (int k = 0; k < DHID; ++k) {
        float w = W[k * 256 + t];
        #pragma unroll
        for (int r = 0; r < ROWS; ++r) acc[r] += xs[r][k] * w;
    }

    const float asv = as_[t], adv = ad_[t];
    const int head = t >> 6, lane = t & 63;
    for (int r = 0; r < ROWS; ++r) {
        int node = base + r;
        if (node >= N) break;
        h[(size_t)node * 256 + t] = __float2bfloat16(acc[r]);
        float vs = acc[r] * asv, vd = acc[r] * adv;
        #pragma unroll
        for (int o = 32; o > 0; o >>= 1) {
            vs += __shfl_down(vs, o, 64);
            vd += __shfl_down(vd, o, 64);
        }
        if (lane == 0) {
            asrc[node * NH + head] = vs;
            adst[node * NH + head] = vd;
        }
    }
}

// ---------------------------------------------------------------- pull-style GAT aggregation
// one wave per dst node. Pass1/2: lane = (slot,head) 16x4, softmax stats via butterfly,
// exp cached in per-wave LDS. Pass3: lane = channel, sequential edges, plain store.
__global__ __launch_bounds__(256) void k_agg(
    const int* __restrict__ rowptr, const int* __restrict__ col,
    const float* __restrict__ asrc, const float* __restrict__ adst,
    const __hip_bfloat16* __restrict__ h, float* __restrict__ outacc, int N)
{
    __shared__ float exs[4][CAP * 4];
    const int lane = threadIdx.x & 63;
    const int wv = threadIdx.x >> 6;
    const int d = (blockIdx.x << 2) + wv;
    if (d >= N) return;
    const int hh = lane & 3, slot = lane >> 2;
    const int r0 = rowptr[d];
    const int deg = rowptr[d + 1] - r0;    // >= 1 (self-loop)

    const float ad = adst[d * 4 + hh];

    // pass 1: leaky logits -> LDS, per-head max
    float mx = -1e30f;
    for (int j = slot; j < deg; j += 16) {
        int s = col[r0 + j];
        float a = asrc[s * 4 + hh] + ad;
        a = (a >= 0.f) ? a : 0.2f * a;
        if (j < CAP) exs[wv][j * 4 + hh] = a;
        mx = fmaxf(mx, a);
    }
    #pragma unroll
    for (int o = 4; o < 64; o <<= 1) mx = fmaxf(mx, __shfl_xor(mx, o, 64));

    // pass 2: exp (cached), per-head sum
    float sm = 0.f;
    for (int j = slot; j < deg; j += 16) {
        float a;
        if (j < CAP) a = exs[wv][j * 4 + hh];
        else {
            int s = col[r0 + j];
            a = asrc[s * 4 + hh] + ad;
            a = (a >= 0.f) ? a : 0.2f * a;
        }
        float ex = __expf(a - mx);
        if (j < CAP) exs[wv][j * 4 + hh] = ex;
        sm += ex;
    }
    #pragma unroll
    for (int o = 4; o < 64; o <<= 1) sm += __shfl_xor(sm, o, 64);

    const float iv = 0.25f / sm;           // fold mean-over-heads
    const float i0 = __shfl(iv, 0), i1 = __shfl(iv, 1), i2 = __shfl(iv, 2), i3 = __shfl(iv, 3);
    const float m0 = __shfl(mx, 0), m1 = __shfl(mx, 1), m2 = __shfl(mx, 2), m3 = __shfl(mx, 3);
    const float d0 = __shfl(ad, 0), d1 = __shfl(ad, 1), d2 = __shfl(ad, 2), d3 = __shfl(ad, 3);

    // pass 3: aggregate; lane = channel
    float acc = 0.f;
    for (int j = 0; j < deg; ++j) {
        int s = col[r0 + j];
        float w0, w1, w2, w3;
        if (j < CAP) {
            w0 = exs[wv][j * 4 + 0] * i0; w1 = exs[wv][j * 4 + 1] * i1;
            w2 = exs[wv][j * 4 + 2] * i2; w3 = exs[wv][j * 4 + 3] * i3;
        } else {   // effectively never (deg > 128)
            float a;
            a = asrc[s * 4 + 0] + d0; a = (a >= 0.f) ? a : 0.2f * a; w0 = __expf(a - m0) * i0;
            a = asrc[s * 4 + 1] + d1; a = (a >= 0.f) ? a : 0.2f * a; w1 = __expf(a - m1) * i1;
            a = asrc[s * 4 + 2] + d2; a = (a >= 0.f) ? a : 0.2f * a; w2 = __expf(a - m2) * i2;
            a = asrc[s * 4 + 3] + d3; a = (a >= 0.f) ? a : 0.2f * a; w3 = __expf(a - m3) * i3;
        }
        const __hip_bfloat16* hs = h + (size_t)s * 256;
        acc += w0 * b2f(hs[lane]) + w1 * b2f(hs[64 + lane]) +
               w2 * b2f(hs[128 + lane]) + w3 * b2f(hs[192 + lane]);
    }
    outacc[(size_t)d * 64 + lane] = acc;
}

// ---------------------------------------------------------------- pool (unchanged from r4)
__global__ __launch_bounds__(256) void k_pool(
    const float* __restrict__ outacc,
    const float* __restrict__ b2_,
    const float* __restrict__ bg, const float* __restrict__ bb,
    const float* __restrict__ bm, const float* __restrict__ bv,
    const int* __restrict__ batch,
    float* __restrict__ pool, float* __restrict__ cnt, int N)
{
    const int lane = threadIdx.x & 63;
    const int wave = threadIdx.x >> 6;
    const int base = blockIdx.x * PNODES;
    int end = base + PNODES; if (end > N) end = N;

    const float scale = bg[lane] * rsqrtf(bv[lane] + EPS);
    const float shift = (b2_[lane] - bm[lane]) * scale + bb[lane];

    float acc = 0.f;
    int cur = -1, cl = 0;
    for (int n = base + wave; n < end; n += 4) {
        int gr = batch[n];
        if (gr != cur) {
            if (cur >= 0) {
                atomicAdd(&pool[cur * 64 + lane], acc);
                if (lane == 0) atomicAdd(&cnt[cur], (float)cl);
            }
            cur = gr; acc = 0.f; cl = 0;
        }
        float v = fmaxf(outacc[(size_t)n * 64 + lane] * scale + shift, 0.f);
        acc += v; ++cl;
    }
    if (cur >= 0) {
        atomicAdd(&pool[cur * 64 + lane], acc);
        if (lane == 0) atomicAdd(&cnt[cur], (float)cl);
    }
}

// ---------------------------------------------------------------- head (unchanged)
__global__ void k_head(const float* __restrict__ pool, const float* __restrict__ cnt,
                       const float* __restrict__ fc1w, const float* __restrict__ fc1b,
                       const float* __restrict__ fc2w, const float* __restrict__ fc2b,
                       float* __restrict__ out)
{
    int g = blockIdx.x;
    int t = threadIdx.x;  // 64 threads
    __shared__ float emb[64];
    __shared__ float z1[32];
    float c = fmaxf(cnt[g], 1.0f);
    emb[t] = pool[g * 64 + t] / c;
    __syncthreads();
    if (t < 32) {
        float s = fc1b[t];
        for (int k = 0; k < 64; ++k) s += emb[k] * fc1w[k * 32 + t];
        z1[t] = fmaxf(s, 0.f);
    }
    __syncthreads();
    if (t < 32) {
        float o = fc2b[t];
        for (int j = 0; j < 32; ++j) o += z1[j] * fc2w[j * 32 + t];
        out[g * 32 + t] = o;
    }
}

// ---------------------------------------------------------------- launch
extern "C" void kernel_launch(void* const* d_in, const int* in_sizes, int n_in,
                              void* d_out, int out_size, void* d_ws, size_t ws_size,
                              hipStream_t stream)
{
    const float* x    = (const float*)d_in[0];
    const int*   ei   = (const int*)d_in[1];
    const int*   batch= (const int*)d_in[2];
    const float* ing  = (const float*)d_in[3];
    const float* inb  = (const float*)d_in[4];
    const float* inm  = (const float*)d_in[5];
    const float* inv  = (const float*)d_in[6];
    const float* W1   = (const float*)d_in[7];
    const float* as1  = (const float*)d_in[8];
    const float* ad1  = (const float*)d_in[9];
    const float* b1   = (const float*)d_in[10];
    const float* bn1g = (const float*)d_in[11];
    const float* bn1b = (const float*)d_in[12];
    const float* bn1m = (const float*)d_in[13];
    const float* bn1v = (const float*)d_in[14];
    const float* W2   = (const float*)d_in[15];
    const float* as2  = (const float*)d_in[16];
    const float* ad2  = (const float*)d_in[17];
    const float* b2   = (const float*)d_in[18];
    const float* bn2g = (const float*)d_in[19];
    const float* bn2b = (const float*)d_in[20];
    const float* bn2m = (const float*)d_in[21];
    const float* bn2v = (const float*)d_in[22];
    const float* fc1w = (const float*)d_in[23];
    const float* fc1b = (const float*)d_in[24];
    const float* fc2w = (const float*)d_in[25];
    const float* fc2b = (const float*)d_in[26];

    const int N = in_sizes[0] / DIN;
    const int E = in_sizes[1] / 2;
    const int G = out_size / DOUT;
    const int Etot = E + N;

    // workspace layout — ~44 MB
    __hip_bfloat16* h = (__hip_bfloat16*)d_ws;            // N*256 bf16
    float* asrc   = (float*)(h + (size_t)N * 256);        // N*4
    float* adst   = asrc + (size_t)N * NH;                // N*4
    float* outacc = adst + (size_t)N * NH;                // N*64
    int*   deg    = (int*)(outacc + (size_t)N * DHID);    // N
    int*   rowptr = deg + N;                              // N+1
    int*   cursor = rowptr + N + 1;                       // N
    int*   col    = cursor + N;                           // E+N
    float* pool   = (float*)(col + Etot);                 // G*64
    float* cnt    = pool + (size_t)G * DHID;              // G

    const int npool = G * DHID + G;
    dim3 b256(256);

    // ---- CSR build (shared by both layers) + zero pool/cnt
    k_init0<<<(N + 255) / 256, b256, 0, stream>>>(deg, pool, N, npool);
    k_hist<<<(E + 255) / 256, b256, 0, stream>>>(ei, deg, E);
    k_scan<<<1, 1024, 0, stream>>>(deg, rowptr, cursor, N);
    k_fill<<<(Etot + 255) / 256, b256, 0, stream>>>(ei, cursor, col, E, N);

    // ---- layer 1
    k_gemm1<<<(N + ROWS - 1) / ROWS, b256, 0, stream>>>(x, ing, inb, inm, inv, W1, as1, ad1,
                                                        h, asrc, adst, N);
    k_agg<<<(N + 3) / 4, b256, 0, stream>>>(rowptr, col, asrc, adst, h, outacc, N);

    // ---- layer 2
    k_gemm2<<<(N + ROWS - 1) / ROWS, b256, 0, stream>>>(outacc, b1, bn1g, bn1b, bn1m, bn1v,
                                                        W2, as2, ad2, h, asrc, adst, N);
    k_agg<<<(N + 3) / 4, b256, 0, stream>>>(rowptr, col, asrc, adst, h, outacc, N);

    // ---- pool + head
    k_pool<<<(N + PNODES - 1) / PNODES, b256, 0, stream>>>(outacc, b2, bn2g, bn2b, bn2m, bn2v,
                                                           batch, pool, cnt, N);
    k_head<<<G, 64, 0, stream>>>(pool, cnt, fc1w, fc1b, fc2w, fc2b, (float*)d_out);
}

// Round 7
// 592.110 us; speedup vs baseline: 1.9000x; 1.1649x over previous
//
#include <hip/hip_runtime.h>
#include <hip/hip_bf16.h>

#define EPS   1e-5f
#define NH    4      // heads
#define DIN   128
#define DHID  64
#define DOUT  32
#define ROWS  8      // nodes per GEMM block
#define PNODES 256   // nodes per k_pool block
#define CAP   128    // per-wave LDS edge capacity in k_agg (deg ~Poisson(17); >128 ~never)

__device__ __forceinline__ float b2f(__hip_bfloat16 v) { return __bfloat162float(v); }

// ---------------------------------------------------------------- init: deg=1 (self-loop), zero pool/cnt
__global__ void k_init0(int* __restrict__ deg, float* __restrict__ pool, int N, int npool) {
    int g = blockIdx.x * blockDim.x + threadIdx.x;
    if (g < N) deg[g] = 1;
    if (g < npool) pool[g] = 0.f;
}

// ---------------------------------------------------------------- CSR build: histogram of dst
__global__ void k_hist(const int* __restrict__ ei, int* __restrict__ deg, int E) {
    int e = blockIdx.x * blockDim.x + threadIdx.x;
    if (e < E) atomicAdd(&deg[ei[E + e]], 1);
}

// ---------------------------------------------------------------- 3-phase parallel exclusive scan
// phase A: block-local exclusive scan (256 nodes/block), block total -> bsum
__global__ __launch_bounds__(256) void k_scan_a(const int* __restrict__ deg,
                                                int* __restrict__ rowptr,
                                                int* __restrict__ bsum, int N) {
    __shared__ int sh[256];
    const int t = threadIdx.x;
    const int i = blockIdx.x * 256 + t;
    int v = (i < N) ? deg[i] : 0;
    sh[t] = v;
    __syncthreads();
    #pragma unroll
    for (int o = 1; o < 256; o <<= 1) {
        int u = (t >= o) ? sh[t - o] : 0;
        __syncthreads();
        sh[t] += u;
        __syncthreads();
    }
    if (i < N) rowptr[i] = sh[t] - v;          // block-local exclusive
    if (t == 255) bsum[blockIdx.x] = sh[255];  // block total
}

// phase B: exclusive scan of block totals (nb <= 256) in one block
__global__ __launch_bounds__(256) void k_scan_b(int* __restrict__ bsum, int nb) {
    __shared__ int sh[256];
    const int t = threadIdx.x;
    int v = (t < nb) ? bsum[t] : 0;
    sh[t] = v;
    __syncthreads();
    #pragma unroll
    for (int o = 1; o < 256; o <<= 1) {
        int u = (t >= o) ? sh[t - o] : 0;
        __syncthreads();
        sh[t] += u;
        __syncthreads();
    }
    if (t < nb) bsum[t] = sh[t] - v;           // exclusive block offsets
}

// phase C: add block offset; emit cursor copy; set rowptr[N]=Etot (known constant)
__global__ __launch_bounds__(256) void k_scan_c(int* __restrict__ rowptr,
                                                int* __restrict__ cursor,
                                                const int* __restrict__ bsum,
                                                int N, int Etot) {
    const int i = blockIdx.x * 256 + threadIdx.x;
    if (i < N) {
        int v = rowptr[i] + bsum[blockIdx.x];
        rowptr[i] = v;
        cursor[i] = v;
    }
    if (i == 0) rowptr[N] = Etot;
}

// ---------------------------------------------------------------- CSR build: scatter src ids (+self-loops)
__global__ void k_fill(const int* __restrict__ ei, int* __restrict__ cursor,
                       int* __restrict__ col, int E, int N) {
    int g = blockIdx.x * blockDim.x + threadIdx.x;
    if (g >= E + N) return;
    int s, d;
    if (g < E) { s = ei[g]; d = ei[E + g]; } else { s = d = g - E; }
    int pos = atomicAdd(&cursor[d], 1);
    col[pos] = s;
}

// ---------------------------------------------------------------- layer-1 GEMM (unchanged)
__global__ __launch_bounds__(256) void k_gemm1(
    const float* __restrict__ x,
    const float* __restrict__ ing, const float* __restrict__ inb,
    const float* __restrict__ inm, const float* __restrict__ inv,
    const float* __restrict__ W,      // [128,256]
    const float* __restrict__ as_, const float* __restrict__ ad_, // [256]
    __hip_bfloat16* __restrict__ h, float* __restrict__ asrc, float* __restrict__ adst, int N)
{
    __shared__ float xs[ROWS][DIN];
    const int t = threadIdx.x;
    const int base = blockIdx.x * ROWS;

    #pragma unroll
    for (int j = 0; j < ROWS * DIN / 256; ++j) {
        int idx = t + j * 256;
        int r = idx >> 7, k = idx & 127;
        int node = base + r;
        float val = 0.f;
        if (node < N) {
            float xv = x[(size_t)node * DIN + k];
            val = (xv - inm[k]) * rsqrtf(inv[k] + EPS) * ing[k] + inb[k];
        }
        xs[r][k] = val;
    }
    __syncthreads();

    float acc[ROWS];
    #pragma unroll
    for (int r = 0; r < ROWS; ++r) acc[r] = 0.f;
    for (int k = 0; k < DIN; ++k) {
        float w = W[k * 256 + t];
        #pragma unroll
        for (int r = 0; r < ROWS; ++r) acc[r] += xs[r][k] * w;
    }

    const float asv = as_[t], adv = ad_[t];
    const int head = t >> 6, lane = t & 63;
    for (int r = 0; r < ROWS; ++r) {
        int node = base + r;
        if (node >= N) break;
        h[(size_t)node * 256 + t] = __float2bfloat16(acc[r]);
        float vs = acc[r] * asv, vd = acc[r] * adv;
        #pragma unroll
        for (int o = 32; o > 0; o >>= 1) {
            vs += __shfl_down(vs, o, 64);
            vd += __shfl_down(vd, o, 64);
        }
        if (lane == 0) {
            asrc[node * NH + head] = vs;
            adst[node * NH + head] = vd;
        }
    }
}

// ---------------------------------------------------------------- layer-2 GEMM (unchanged)
__global__ __launch_bounds__(256) void k_gemm2(
    const float* __restrict__ outacc,
    const float* __restrict__ b1,
    const float* __restrict__ bg, const float* __restrict__ bb,
    const float* __restrict__ bm, const float* __restrict__ bv,
    const float* __restrict__ W,      // [64,256]
    const float* __restrict__ as_, const float* __restrict__ ad_,
    __hip_bfloat16* __restrict__ h, float* __restrict__ asrc, float* __restrict__ adst, int N)
{
    __shared__ float xs[ROWS][DHID];
    const int t = threadIdx.x;
    const int base = blockIdx.x * ROWS;

    #pragma unroll
    for (int j = 0; j < ROWS * DHID / 256; ++j) {
        int idx = t + j * 256;
        int r = idx >> 6, c = idx & 63;
        int node = base + r;
        float val = 0.f;
        if (node < N) {
            float raw = outacc[(size_t)node * DHID + c] + b1[c];
            float bnv = (raw - bm[c]) * rsqrtf(bv[c] + EPS) * bg[c] + bb[c];
            val = fmaxf(bnv, 0.f);
        }
        xs[r][c] = val;
    }
    __syncthreads();

    float acc[ROWS];
    #pragma unroll
    for (int r = 0; r < ROWS; ++r) acc[r] = 0.f;
    for (int k = 0; k < DHID; ++k) {
        float w = W[k * 256 + t];
        #pragma unroll
        for (int r = 0; r < ROWS; ++r) acc[r] += xs[r][k] * w;
    }

    const float asv = as_[t], adv = ad_[t];
    const int head = t >> 6, lane = t & 63;
    for (int r = 0; r < ROWS; ++r) {
        int node = base + r;
        if (node >= N) break;
        h[(size_t)node * 256 + t] = __float2bfloat16(acc[r]);
        float vs = acc[r] * asv, vd = acc[r] * adv;
        #pragma unroll
        for (int o = 32; o > 0; o >>= 1) {
            vs += __shfl_down(vs, o, 64);
            vd += __shfl_down(vd, o, 64);
        }
        if (lane == 0) {
            asrc[node * NH + head] = vs;
            adst[node * NH + head] = vd;
        }
    }
}

// ---------------------------------------------------------------- pull-style GAT aggregation (unchanged)
__global__ __launch_bounds__(256) void k_agg(
    const int* __restrict__ rowptr, const int* __restrict__ col,
    const float* __restrict__ asrc, const float* __restrict__ adst,
    const __hip_bfloat16* __restrict__ h, float* __restrict__ outacc, int N)
{
    __shared__ float exs[4][CAP * 4];
    const int lane = threadIdx.x & 63;
    const int wv = threadIdx.x >> 6;
    const int d = (blockIdx.x << 2) + wv;
    if (d >= N) return;
    const int hh = lane & 3, slot = lane >> 2;
    const int r0 = rowptr[d];
    const int deg = rowptr[d + 1] - r0;    // >= 1 (self-loop)

    const float ad = adst[d * 4 + hh];

    // pass 1: leaky logits -> LDS, per-head max
    float mx = -1e30f;
    for (int j = slot; j < deg; j += 16) {
        int s = col[r0 + j];
        float a = asrc[s * 4 + hh] + ad;
        a = (a >= 0.f) ? a : 0.2f * a;
        if (j < CAP) exs[wv][j * 4 + hh] = a;
        mx = fmaxf(mx, a);
    }
    #pragma unroll
    for (int o = 4; o < 64; o <<= 1) mx = fmaxf(mx, __shfl_xor(mx, o, 64));

    // pass 2: exp (cached), per-head sum
    float sm = 0.f;
    for (int j = slot; j < deg; j += 16) {
        float a;
        if (j < CAP) a = exs[wv][j * 4 + hh];
        else {
            int s = col[r0 + j];
            a = asrc[s * 4 + hh] + ad;
            a = (a >= 0.f) ? a : 0.2f * a;
        }
        float ex = __expf(a - mx);
        if (j < CAP) exs[wv][j * 4 + hh] = ex;
        sm += ex;
    }
    #pragma unroll
    for (int o = 4; o < 64; o <<= 1) sm += __shfl_xor(sm, o, 64);

    const float iv = 0.25f / sm;           // fold mean-over-heads
    const float i0 = __shfl(iv, 0), i1 = __shfl(iv, 1), i2 = __shfl(iv, 2), i3 = __shfl(iv, 3);
    const float m0 = __shfl(mx, 0), m1 = __shfl(mx, 1), m2 = __shfl(mx, 2), m3 = __shfl(mx, 3);
    const float d0 = __shfl(ad, 0), d1 = __shfl(ad, 1), d2 = __shfl(ad, 2), d3 = __shfl(ad, 3);

    // pass 3: aggregate; lane = channel
    float acc = 0.f;
    for (int j = 0; j < deg; ++j) {
        int s = col[r0 + j];
        float w0, w1, w2, w3;
        if (j < CAP) {
            w0 = exs[wv][j * 4 + 0] * i0; w1 = exs[wv][j * 4 + 1] * i1;
            w2 = exs[wv][j * 4 + 2] * i2; w3 = exs[wv][j * 4 + 3] * i3;
        } else {   // effectively never (deg > 128)
            float a;
            a = asrc[s * 4 + 0] + d0; a = (a >= 0.f) ? a : 0.2f * a; w0 = __expf(a - m0) * i0;
            a = asrc[s * 4 + 1] + d1; a = (a >= 0.f) ? a : 0.2f * a; w1 = __expf(a - m1) * i1;
            a = asrc[s * 4 + 2] + d2; a = (a >= 0.f) ? a : 0.2f * a; w2 = __expf(a - m2) * i2;
            a = asrc[s * 4 + 3] + d3; a = (a >= 0.f) ? a : 0.2f * a; w3 = __expf(a - m3) * i3;
        }
        const __hip_bfloat16* hs = h + (size_t)s * 256;
        acc += w0 * b2f(hs[lane]) + w1 * b2f(hs[64 + lane]) +
               w2 * b2f(hs[128 + lane]) + w3 * b2f(hs[192 + lane]);
    }
    outacc[(size_t)d * 64 + lane] = acc;
}

// ---------------------------------------------------------------- pool (unchanged)
__global__ __launch_bounds__(256) void k_pool(
    const float* __restrict__ outacc,
    const float* __restrict__ b2_,
    const float* __restrict__ bg, const float* __restrict__ bb,
    const float* __restrict__ bm, const float* __restrict__ bv,
    const int* __restrict__ batch,
    float* __restrict__ pool, float* __restrict__ cnt, int N)
{
    const int lane = threadIdx.x & 63;
    const int wave = threadIdx.x >> 6;
    const int base = blockIdx.x * PNODES;
    int end = base + PNODES; if (end > N) end = N;

    const float scale = bg[lane] * rsqrtf(bv[lane] + EPS);
    const float shift = (b2_[lane] - bm[lane]) * scale + bb[lane];

    float acc = 0.f;
    int cur = -1, cl = 0;
    for (int n = base + wave; n < end; n += 4) {
        int gr = batch[n];
        if (gr != cur) {
            if (cur >= 0) {
                atomicAdd(&pool[cur * 64 + lane], acc);
                if (lane == 0) atomicAdd(&cnt[cur], (float)cl);
            }
            cur = gr; acc = 0.f; cl = 0;
        }
        float v = fmaxf(outacc[(size_t)n * 64 + lane] * scale + shift, 0.f);
        acc += v; ++cl;
    }
    if (cur >= 0) {
        atomicAdd(&pool[cur * 64 + lane], acc);
        if (lane == 0) atomicAdd(&cnt[cur], (float)cl);
    }
}

// ---------------------------------------------------------------- head (unchanged)
__global__ void k_head(const float* __restrict__ pool, const float* __restrict__ cnt,
                       const float* __restrict__ fc1w, const float* __restrict__ fc1b,
                       const float* __restrict__ fc2w, const float* __restrict__ fc2b,
                       float* __restrict__ out)
{
    int g = blockIdx.x;
    int t = threadIdx.x;  // 64 threads
    __shared__ float emb[64];
    __shared__ float z1[32];
    float c = fmaxf(cnt[g], 1.0f);
    emb[t] = pool[g * 64 + t] / c;
    __syncthreads();
    if (t < 32) {
        float s = fc1b[t];
        for (int k = 0; k < 64; ++k) s += emb[k] * fc1w[k * 32 + t];
        z1[t] = fmaxf(s, 0.f);
    }
    __syncthreads();
    if (t < 32) {
        float o = fc2b[t];
        for (int j = 0; j < 32; ++j) o += z1[j] * fc2w[j * 32 + t];
        out[g * 32 + t] = o;
    }
}

// ---------------------------------------------------------------- launch
extern "C" void kernel_launch(void* const* d_in, const int* in_sizes, int n_in,
                              void* d_out, int out_size, void* d_ws, size_t ws_size,
                              hipStream_t stream)
{
    const float* x    = (const float*)d_in[0];
    const int*   ei   = (const int*)d_in[1];
    const int*   batch= (const int*)d_in[2];
    const float* ing  = (const float*)d_in[3];
    const float* inb  = (const float*)d_in[4];
    const float* inm  = (const float*)d_in[5];
    const float* inv  = (const float*)d_in[6];
    const float* W1   = (const float*)d_in[7];
    const float* as1  = (const float*)d_in[8];
    const float* ad1  = (const float*)d_in[9];
    const float* b1   = (const float*)d_in[10];
    const float* bn1g = (const float*)d_in[11];
    const float* bn1b = (const float*)d_in[12];
    const float* bn1m = (const float*)d_in[13];
    const float* bn1v = (const float*)d_in[14];
    const float* W2   = (const float*)d_in[15];
    const float* as2  = (const float*)d_in[16];
    const float* ad2  = (const float*)d_in[17];
    const float* b2   = (const float*)d_in[18];
    const float* bn2g = (const float*)d_in[19];
    const float* bn2b = (const float*)d_in[20];
    const float* bn2m = (const float*)d_in[21];
    const float* bn2v = (const float*)d_in[22];
    const float* fc1w = (const float*)d_in[23];
    const float* fc1b = (const float*)d_in[24];
    const float* fc2w = (const float*)d_in[25];
    const float* fc2b = (const float*)d_in[26];

    const int N = in_sizes[0] / DIN;
    const int E = in_sizes[1] / 2;
    const int G = out_size / DOUT;
    const int Etot = E + N;

    // workspace layout — ~44 MB
    __hip_bfloat16* h = (__hip_bfloat16*)d_ws;            // N*256 bf16
    float* asrc   = (float*)(h + (size_t)N * 256);        // N*4
    float* adst   = asrc + (size_t)N * NH;                // N*4
    float* outacc = adst + (size_t)N * NH;                // N*64
    int*   deg    = (int*)(outacc + (size_t)N * DHID);    // N
    int*   rowptr = deg + N;                              // N+1
    int*   cursor = rowptr + N + 1;                       // N
    int*   col    = cursor + N;                           // E+N
    float* pool   = (float*)(col + Etot);                 // G*64
    float* cnt    = pool + (size_t)G * DHID;              // G
    int*   bsum   = (int*)(cnt + G);                      // ceil(N/256) <= 256

    const int npool = G * DHID + G;
    const int nScanBlk = (N + 255) / 256;                 // 196 for N=50000 (<=256 required)
    dim3 b256(256);

    // ---- CSR build (shared by both layers) + zero pool/cnt
    k_init0<<<(N + 255) / 256, b256, 0, stream>>>(deg, pool, N, npool);
    k_hist<<<(E + 255) / 256, b256, 0, stream>>>(ei, deg, E);
    k_scan_a<<<nScanBlk, b256, 0, stream>>>(deg, rowptr, bsum, N);
    k_scan_b<<<1, b256, 0, stream>>>(bsum, nScanBlk);
    k_scan_c<<<nScanBlk, b256, 0, stream>>>(rowptr, cursor, bsum, N, Etot);
    k_fill<<<(Etot + 255) / 256, b256, 0, stream>>>(ei, cursor, col, E, N);

    // ---- layer 1
    k_gemm1<<<(N + ROWS - 1) / ROWS, b256, 0, stream>>>(x, ing, inb, inm, inv, W1, as1, ad1,
                                                        h, asrc, adst, N);
    k_agg<<<(N + 3) / 4, b256, 0, stream>>>(rowptr, col, asrc, adst, h, outacc, N);

    // ---- layer 2
    k_gemm2<<<(N + ROWS - 1) / ROWS, b256, 0, stream>>>(outacc, b1, bn1g, bn1b, bn1m, bn1v,
                                                        W2, as2, ad2, h, asrc, adst, N);
    k_agg<<<(N + 3) / 4, b256, 0, stream>>>(rowptr, col, asrc, adst, h, outacc, N);

    // ---- pool + head
    k_pool<<<(N + PNODES - 1) / PNODES, b256, 0, stream>>>(outacc, b2, bn2g, bn2b, bn2m, bn2v,
                                                           batch, pool, cnt, N);
    k_head<<<G, 64, 0, stream>>>(pool, cnt, fc1w, fc1b, fc2w, fc2b, (float*)d_out);
}

// Round 8
// 507.715 us; speedup vs baseline: 2.2158x; 1.1662x over previous
//
#include <hip/hip_runtime.h>
#include <hip/hip_bf16.h>

#define EPS   1e-5f
#define NH    4      // heads
#define DIN   128
#define DHID  64
#define DOUT  32
#define ROWS  8      // nodes per GEMM block
#define PNODES 256   // nodes per k_pool block
#define CAP   128    // per-wave LDS edge capacity in k_agg (deg ~Poisson(17); >128 ~never)

__device__ __forceinline__ float b2f(__hip_bfloat16 v) { return __bfloat162float(v); }
__device__ __forceinline__ float us2f(unsigned short u) {   // raw bf16 bits -> f32
    return __uint_as_float((unsigned)u << 16);
}
__device__ __forceinline__ float lrelu(float a) { return (a >= 0.f) ? a : 0.2f * a; }

// ---------------------------------------------------------------- init: deg=1 (self-loop), zero pool/cnt
__global__ void k_init0(int* __restrict__ deg, float* __restrict__ pool, int N, int npool) {
    int g = blockIdx.x * blockDim.x + threadIdx.x;
    if (g < N) deg[g] = 1;
    if (g < npool) pool[g] = 0.f;
}

// ---------------------------------------------------------------- CSR build: histogram of dst
__global__ void k_hist(const int* __restrict__ ei, int* __restrict__ deg, int E) {
    int e = blockIdx.x * blockDim.x + threadIdx.x;
    if (e < E) atomicAdd(&deg[ei[E + e]], 1);
}

// ---------------------------------------------------------------- 3-phase parallel exclusive scan
__global__ __launch_bounds__(256) void k_scan_a(const int* __restrict__ deg,
                                                int* __restrict__ rowptr,
                                                int* __restrict__ bsum, int N) {
    __shared__ int sh[256];
    const int t = threadIdx.x;
    const int i = blockIdx.x * 256 + t;
    int v = (i < N) ? deg[i] : 0;
    sh[t] = v;
    __syncthreads();
    #pragma unroll
    for (int o = 1; o < 256; o <<= 1) {
        int u = (t >= o) ? sh[t - o] : 0;
        __syncthreads();
        sh[t] += u;
        __syncthreads();
    }
    if (i < N) rowptr[i] = sh[t] - v;
    if (t == 255) bsum[blockIdx.x] = sh[255];
}

__global__ __launch_bounds__(256) void k_scan_b(int* __restrict__ bsum, int nb) {
    __shared__ int sh[256];
    const int t = threadIdx.x;
    int v = (t < nb) ? bsum[t] : 0;
    sh[t] = v;
    __syncthreads();
    #pragma unroll
    for (int o = 1; o < 256; o <<= 1) {
        int u = (t >= o) ? sh[t - o] : 0;
        __syncthreads();
        sh[t] += u;
        __syncthreads();
    }
    if (t < nb) bsum[t] = sh[t] - v;
}

__global__ __launch_bounds__(256) void k_scan_c(int* __restrict__ rowptr,
                                                int* __restrict__ cursor,
                                                const int* __restrict__ bsum,
                                                int N, int Etot) {
    const int i = blockIdx.x * 256 + threadIdx.x;
    if (i < N) {
        int v = rowptr[i] + bsum[blockIdx.x];
        rowptr[i] = v;
        cursor[i] = v;
    }
    if (i == 0) rowptr[N] = Etot;
}

// ---------------------------------------------------------------- CSR build: scatter src ids (+self-loops)
__global__ void k_fill(const int* __restrict__ ei, int* __restrict__ cursor,
                       int* __restrict__ col, int E, int N) {
    int g = blockIdx.x * blockDim.x + threadIdx.x;
    if (g >= E + N) return;
    int s, d;
    if (g < E) { s = ei[g]; d = ei[E + g]; } else { s = d = g - E; }
    int pos = atomicAdd(&cursor[d], 1);
    col[pos] = s;
}

// ---------------------------------------------------------------- layer-1 GEMM
// h stored TRANSPOSED: h[node][channel][head]  (element index = c*4 + hd)
__global__ __launch_bounds__(256) void k_gemm1(
    const float* __restrict__ x,
    const float* __restrict__ ing, const float* __restrict__ inb,
    const float* __restrict__ inm, const float* __restrict__ inv,
    const float* __restrict__ W,      // [128,256]
    const float* __restrict__ as_, const float* __restrict__ ad_, // [256]
    __hip_bfloat16* __restrict__ h, float* __restrict__ asrc, float* __restrict__ adst, int N)
{
    __shared__ float xs[ROWS][DIN];
    __shared__ __hip_bfloat16 hsh[ROWS][256];
    const int t = threadIdx.x;
    const int base = blockIdx.x * ROWS;

    #pragma unroll
    for (int j = 0; j < ROWS * DIN / 256; ++j) {
        int idx = t + j * 256;
        int r = idx >> 7, k = idx & 127;
        int node = base + r;
        float val = 0.f;
        if (node < N) {
            float xv = x[(size_t)node * DIN + k];
            val = (xv - inm[k]) * rsqrtf(inv[k] + EPS) * ing[k] + inb[k];
        }
        xs[r][k] = val;
    }
    __syncthreads();

    float acc[ROWS];
    #pragma unroll
    for (int r = 0; r < ROWS; ++r) acc[r] = 0.f;
    for (int k = 0; k < DIN; ++k) {
        float w = W[k * 256 + t];
        #pragma unroll
        for (int r = 0; r < ROWS; ++r) acc[r] += xs[r][k] * w;
    }

    const float asv = as_[t], adv = ad_[t];
    const int head = t >> 6, lane = t & 63;
    for (int r = 0; r < ROWS; ++r) {
        int node = base + r;
        if (node >= N) break;
        hsh[r][lane * 4 + head] = __float2bfloat16(acc[r]);   // transposed repack
        float vs = acc[r] * asv, vd = acc[r] * adv;
        #pragma unroll
        for (int o = 32; o > 0; o >>= 1) {
            vs += __shfl_down(vs, o, 64);
            vd += __shfl_down(vd, o, 64);
        }
        if (lane == 0) {
            asrc[node * NH + head] = vs;
            adst[node * NH + head] = vd;
        }
    }
    __syncthreads();
    for (int r = 0; r < ROWS; ++r) {
        int node = base + r;
        if (node >= N) break;
        h[(size_t)node * 256 + t] = hsh[r][t];                // coalesced store
    }
}

// ---------------------------------------------------------------- layer-2 GEMM (same transposed h)
__global__ __launch_bounds__(256) void k_gemm2(
    const float* __restrict__ outacc,
    const float* __restrict__ b1,
    const float* __restrict__ bg, const float* __restrict__ bb,
    const float* __restrict__ bm, const float* __restrict__ bv,
    const float* __restrict__ W,      // [64,256]
    const float* __restrict__ as_, const float* __restrict__ ad_,
    __hip_bfloat16* __restrict__ h, float* __restrict__ asrc, float* __restrict__ adst, int N)
{
    __shared__ float xs[ROWS][DHID];
    __shared__ __hip_bfloat16 hsh[ROWS][256];
    const int t = threadIdx.x;
    const int base = blockIdx.x * ROWS;

    #pragma unroll
    for (int j = 0; j < ROWS * DHID / 256; ++j) {
        int idx = t + j * 256;
        int r = idx >> 6, c = idx & 63;
        int node = base + r;
        float val = 0.f;
        if (node < N) {
            float raw = outacc[(size_t)node * DHID + c] + b1[c];
            float bnv = (raw - bm[c]) * rsqrtf(bv[c] + EPS) * bg[c] + bb[c];
            val = fmaxf(bnv, 0.f);
        }
        xs[r][c] = val;
    }
    __syncthreads();

    float acc[ROWS];
    #pragma unroll
    for (int r = 0; r < ROWS; ++r) acc[r] = 0.f;
    for (int k = 0; k < DHID; ++k) {
        float w = W[k * 256 + t];
        #pragma unroll
        for (int r = 0; r < ROWS; ++r) acc[r] += xs[r][k] * w;
    }

    const float asv = as_[t], adv = ad_[t];
    const int head = t >> 6, lane = t & 63;
    for (int r = 0; r < ROWS; ++r) {
        int node = base + r;
        if (node >= N) break;
        hsh[r][lane * 4 + head] = __float2bfloat16(acc[r]);
        float vs = acc[r] * asv, vd = acc[r] * adv;
        #pragma unroll
        for (int o = 32; o > 0; o >>= 1) {
            vs += __shfl_down(vs, o, 64);
            vd += __shfl_down(vd, o, 64);
        }
        if (lane == 0) {
            asrc[node * NH + head] = vs;
            adst[node * NH + head] = vd;
        }
    }
    __syncthreads();
    for (int r = 0; r < ROWS; ++r) {
        int node = base + r;
        if (node >= N) break;
        h[(size_t)node * 256 + t] = hsh[r][t];
    }
}

// ---------------------------------------------------------------- pull-style GAT aggregation (REWORKED)
// one wave per dst. Pass1/2: lane = edge, float4 asrc gather, butterfly per-head max/sum.
// Pass3: lane = channel, one ushort4 (4 bf16 heads) gather per edge, col+weights from LDS.
__global__ __launch_bounds__(256) void k_agg(
    const int* __restrict__ rowptr, const int* __restrict__ col,
    const float* __restrict__ asrc, const float* __restrict__ adst,
    const __hip_bfloat16* __restrict__ h, float* __restrict__ outacc, int N)
{
    __shared__ float4 exs[4][CAP];
    __shared__ int    cols[4][CAP];
    const int lane = threadIdx.x & 63;
    const int wv   = threadIdx.x >> 6;
    const int d = (blockIdx.x << 2) + wv;
    if (d >= N) return;
    const int r0  = rowptr[d];
    const int deg = rowptr[d + 1] - r0;        // >= 1 (self-loop)

    const float4 ad4 = ((const float4*)adst)[d];
    const float4* __restrict__ as4 = (const float4*)asrc;

    // pass 1: logits (leaky) -> LDS, per-head max
    float mx0 = -1e30f, mx1 = -1e30f, mx2 = -1e30f, mx3 = -1e30f;
    for (int j = lane; j < deg; j += 64) {
        int s = col[r0 + j];
        float4 a = as4[s];
        float a0 = lrelu(a.x + ad4.x), a1 = lrelu(a.y + ad4.y);
        float a2 = lrelu(a.z + ad4.z), a3 = lrelu(a.w + ad4.w);
        if (j < CAP) { cols[wv][j] = s; exs[wv][j] = make_float4(a0, a1, a2, a3); }
        mx0 = fmaxf(mx0, a0); mx1 = fmaxf(mx1, a1);
        mx2 = fmaxf(mx2, a2); mx3 = fmaxf(mx3, a3);
    }
    #pragma unroll
    for (int o = 1; o < 64; o <<= 1) {
        mx0 = fmaxf(mx0, __shfl_xor(mx0, o, 64));
        mx1 = fmaxf(mx1, __shfl_xor(mx1, o, 64));
        mx2 = fmaxf(mx2, __shfl_xor(mx2, o, 64));
        mx3 = fmaxf(mx3, __shfl_xor(mx3, o, 64));
    }

    // pass 2: exp (cached in LDS), per-head sum
    float sm0 = 0.f, sm1 = 0.f, sm2 = 0.f, sm3 = 0.f;
    for (int j = lane; j < deg; j += 64) {
        float a0, a1, a2, a3;
        if (j < CAP) { float4 a = exs[wv][j]; a0 = a.x; a1 = a.y; a2 = a.z; a3 = a.w; }
        else {
            int s = col[r0 + j];
            float4 a = as4[s];
            a0 = lrelu(a.x + ad4.x); a1 = lrelu(a.y + ad4.y);
            a2 = lrelu(a.z + ad4.z); a3 = lrelu(a.w + ad4.w);
        }
        float e0 = __expf(a0 - mx0), e1 = __expf(a1 - mx1);
        float e2 = __expf(a2 - mx2), e3 = __expf(a3 - mx3);
        if (j < CAP) exs[wv][j] = make_float4(e0, e1, e2, e3);
        sm0 += e0; sm1 += e1; sm2 += e2; sm3 += e3;
    }
    #pragma unroll
    for (int o = 1; o < 64; o <<= 1) {
        sm0 += __shfl_xor(sm0, o, 64);
        sm1 += __shfl_xor(sm1, o, 64);
        sm2 += __shfl_xor(sm2, o, 64);
        sm3 += __shfl_xor(sm3, o, 64);
    }
    const float i0 = 0.25f / sm0, i1 = 0.25f / sm1, i2 = 0.25f / sm2, i3 = 0.25f / sm3;

    // pass 3: aggregate; lane = channel; h gather is one dwordx2 per edge
    const ushort4* __restrict__ hv = (const ushort4*)h;   // [node*64 + channel]
    float acc = 0.f;
    for (int j = 0; j < deg; ++j) {
        int s; float w0, w1, w2, w3;
        if (j < CAP) {
            s = cols[wv][j];
            float4 w = exs[wv][j];
            w0 = w.x * i0; w1 = w.y * i1; w2 = w.z * i2; w3 = w.w * i3;
        } else {            // effectively never (deg > 128)
            s = col[r0 + j];
            float4 a = as4[s];
            w0 = __expf(lrelu(a.x + ad4.x) - mx0) * i0;
            w1 = __expf(lrelu(a.y + ad4.y) - mx1) * i1;
            w2 = __expf(lrelu(a.z + ad4.z) - mx2) * i2;
            w3 = __expf(lrelu(a.w + ad4.w) - mx3) * i3;
        }
        ushort4 v = hv[(size_t)s * 64 + lane];
        acc += w0 * us2f(v.x) + w1 * us2f(v.y) + w2 * us2f(v.z) + w3 * us2f(v.w);
    }
    outacc[(size_t)d * 64 + lane] = acc;
}

// ---------------------------------------------------------------- pool (unchanged)
__global__ __launch_bounds__(256) void k_pool(
    const float* __restrict__ outacc,
    const float* __restrict__ b2_,
    const float* __restrict__ bg, const float* __restrict__ bb,
    const float* __restrict__ bm, const float* __restrict__ bv,
    const int* __restrict__ batch,
    float* __restrict__ pool, float* __restrict__ cnt, int N)
{
    const int lane = threadIdx.x & 63;
    const int wave = threadIdx.x >> 6;
    const int base = blockIdx.x * PNODES;
    int end = base + PNODES; if (end > N) end = N;

    const float scale = bg[lane] * rsqrtf(bv[lane] + EPS);
    const float shift = (b2_[lane] - bm[lane]) * scale + bb[lane];

    float acc = 0.f;
    int cur = -1, cl = 0;
    for (int n = base + wave; n < end; n += 4) {
        int gr = batch[n];
        if (gr != cur) {
            if (cur >= 0) {
                atomicAdd(&pool[cur * 64 + lane], acc);
                if (lane == 0) atomicAdd(&cnt[cur], (float)cl);
            }
            cur = gr; acc = 0.f; cl = 0;
        }
        float v = fmaxf(outacc[(size_t)n * 64 + lane] * scale + shift, 0.f);
        acc += v; ++cl;
    }
    if (cur >= 0) {
        atomicAdd(&pool[cur * 64 + lane], acc);
        if (lane == 0) atomicAdd(&cnt[cur], (float)cl);
    }
}

// ---------------------------------------------------------------- head (unchanged)
__global__ void k_head(const float* __restrict__ pool, const float* __restrict__ cnt,
                       const float* __restrict__ fc1w, const float* __restrict__ fc1b,
                       const float* __restrict__ fc2w, const float* __restrict__ fc2b,
                       float* __restrict__ out)
{
    int g = blockIdx.x;
    int t = threadIdx.x;  // 64 threads
    __shared__ float emb[64];
    __shared__ float z1[32];
    float c = fmaxf(cnt[g], 1.0f);
    emb[t] = pool[g * 64 + t] / c;
    __syncthreads();
    if (t < 32) {
        float s = fc1b[t];
        for (int k = 0; k < 64; ++k) s += emb[k] * fc1w[k * 32 + t];
        z1[t] = fmaxf(s, 0.f);
    }
    __syncthreads();
    if (t < 32) {
        float o = fc2b[t];
        for (int j = 0; j < 32; ++j) o += z1[j] * fc2w[j * 32 + t];
        out[g * 32 + t] = o;
    }
}

// ---------------------------------------------------------------- launch
extern "C" void kernel_launch(void* const* d_in, const int* in_sizes, int n_in,
                              void* d_out, int out_size, void* d_ws, size_t ws_size,
                              hipStream_t stream)
{
    const float* x    = (const float*)d_in[0];
    const int*   ei   = (const int*)d_in[1];
    const int*   batch= (const int*)d_in[2];
    const float* ing  = (const float*)d_in[3];
    const float* inb  = (const float*)d_in[4];
    const float* inm  = (const float*)d_in[5];
    const float* inv  = (const float*)d_in[6];
    const float* W1   = (const float*)d_in[7];
    const float* as1  = (const float*)d_in[8];
    const float* ad1  = (const float*)d_in[9];
    const float* b1   = (const float*)d_in[10];
    const float* bn1g = (const float*)d_in[11];
    const float* bn1b = (const float*)d_in[12];
    const float* bn1m = (const float*)d_in[13];
    const float* bn1v = (const float*)d_in[14];
    const float* W2   = (const float*)d_in[15];
    const float* as2  = (const float*)d_in[16];
    const float* ad2  = (const float*)d_in[17];
    const float* b2   = (const float*)d_in[18];
    const float* bn2g = (const float*)d_in[19];
    const float* bn2b = (const float*)d_in[20];
    const float* bn2m = (const float*)d_in[21];
    const float* bn2v = (const float*)d_in[22];
    const float* fc1w = (const float*)d_in[23];
    const float* fc1b = (const float*)d_in[24];
    const float* fc2w = (const float*)d_in[25];
    const float* fc2b = (const float*)d_in[26];

    const int N = in_sizes[0] / DIN;
    const int E = in_sizes[1] / 2;
    const int G = out_size / DOUT;
    const int Etot = E + N;

    // workspace layout — ~44 MB
    __hip_bfloat16* h = (__hip_bfloat16*)d_ws;            // N*256 bf16 (transposed [n][c][hd])
    float* asrc   = (float*)(h + (size_t)N * 256);        // N*4
    float* adst   = asrc + (size_t)N * NH;                // N*4
    float* outacc = adst + (size_t)N * NH;                // N*64
    int*   deg    = (int*)(outacc + (size_t)N * DHID);    // N
    int*   rowptr = deg + N;                              // N+1
    int*   cursor = rowptr + N + 1;                       // N
    int*   col    = cursor + N;                           // E+N
    float* pool   = (float*)(col + Etot);                 // G*64
    float* cnt    = pool + (size_t)G * DHID;              // G
    int*   bsum   = (int*)(cnt + G);                      // ceil(N/256) <= 256

    const int npool = G * DHID + G;
    const int nScanBlk = (N + 255) / 256;                 // 196 for N=50000 (<=256 required)
    dim3 b256(256);

    // ---- CSR build (shared by both layers) + zero pool/cnt
    k_init0<<<(N + 255) / 256, b256, 0, stream>>>(deg, pool, N, npool);
    k_hist<<<(E + 255) / 256, b256, 0, stream>>>(ei, deg, E);
    k_scan_a<<<nScanBlk, b256, 0, stream>>>(deg, rowptr, bsum, N);
    k_scan_b<<<1, b256, 0, stream>>>(bsum, nScanBlk);
    k_scan_c<<<nScanBlk, b256, 0, stream>>>(rowptr, cursor, bsum, N, Etot);
    k_fill<<<(Etot + 255) / 256, b256, 0, stream>>>(ei, cursor, col, E, N);

    // ---- layer 1
    k_gemm1<<<(N + ROWS - 1) / ROWS, b256, 0, stream>>>(x, ing, inb, inm, inv, W1, as1, ad1,
                                                        h, asrc, adst, N);
    k_agg<<<(N + 3) / 4, b256, 0, stream>>>(rowptr, col, asrc, adst, h, outacc, N);

    // ---- layer 2
    k_gemm2<<<(N + ROWS - 1) / ROWS, b256, 0, stream>>>(outacc, b1, bn1g, bn1b, bn1m, bn1v,
                                                        W2, as2, ad2, h, asrc, adst, N);
    k_agg<<<(N + 3) / 4, b256, 0, stream>>>(rowptr, col, asrc, adst, h, outacc, N);

    // ---- pool + head
    k_pool<<<(N + PNODES - 1) / PNODES, b256, 0, stream>>>(outacc, b2, bn2g, bn2b, bn2m, bn2v,
                                                           batch, pool, cnt, N);
    k_head<<<G, 64, 0, stream>>>(pool, cnt, fc1w, fc1b, fc2w, fc2b, (float*)d_out);
}

// Round 9
// 486.820 us; speedup vs baseline: 2.3110x; 1.0429x over previous
//
#include <hip/hip_runtime.h>
#include <hip/hip_bf16.h>

#define EPS   1e-5f
#define NH    4      // heads
#define DIN   128
#define DHID  64
#define DOUT  32
#define ROWS  8      // nodes per gemm2 block
#define PNODES 256   // nodes per k_pool block
#define CAP   128    // per-wave LDS edge capacity in k_agg
#define GM    32     // rows per k_gemm1 (MFMA) block

typedef __attribute__((ext_vector_type(8))) short short8;   // 8 bf16 (4 VGPRs)
typedef __attribute__((ext_vector_type(4))) float f32x4;    // MFMA accumulator

__device__ __forceinline__ float b2f(__hip_bfloat16 v) { return __bfloat162float(v); }
__device__ __forceinline__ float us2f(unsigned short u) {   // raw bf16 bits -> f32
    return __uint_as_float((unsigned)u << 16);
}
__device__ __forceinline__ unsigned short f2us(float v) {   // f32 -> bf16 bits (RN)
    __hip_bfloat16 hb = __float2bfloat16(v);
    return *(unsigned short*)&hb;
}
__device__ __forceinline__ float lrelu(float a) { return (a >= 0.f) ? a : 0.2f * a; }

// ---------------------------------------------------------------- init: deg=1 (self-loop), zero pool/cnt
__global__ void k_init0(int* __restrict__ deg, float* __restrict__ pool, int N, int npool) {
    int g = blockIdx.x * blockDim.x + threadIdx.x;
    if (g < N) deg[g] = 1;
    if (g < npool) pool[g] = 0.f;
}

// ---------------------------------------------------------------- CSR build: histogram of dst
__global__ void k_hist(const int* __restrict__ ei, int* __restrict__ deg, int E) {
    int e = blockIdx.x * blockDim.x + threadIdx.x;
    if (e < E) atomicAdd(&deg[ei[E + e]], 1);
}

// ---------------------------------------------------------------- 3-phase parallel exclusive scan
__global__ __launch_bounds__(256) void k_scan_a(const int* __restrict__ deg,
                                                int* __restrict__ rowptr,
                                                int* __restrict__ bsum, int N) {
    __shared__ int sh[256];
    const int t = threadIdx.x;
    const int i = blockIdx.x * 256 + t;
    int v = (i < N) ? deg[i] : 0;
    sh[t] = v;
    __syncthreads();
    #pragma unroll
    for (int o = 1; o < 256; o <<= 1) {
        int u = (t >= o) ? sh[t - o] : 0;
        __syncthreads();
        sh[t] += u;
        __syncthreads();
    }
    if (i < N) rowptr[i] = sh[t] - v;
    if (t == 255) bsum[blockIdx.x] = sh[255];
}

__global__ __launch_bounds__(256) void k_scan_b(int* __restrict__ bsum, int nb) {
    __shared__ int sh[256];
    const int t = threadIdx.x;
    int v = (t < nb) ? bsum[t] : 0;
    sh[t] = v;
    __syncthreads();
    #pragma unroll
    for (int o = 1; o < 256; o <<= 1) {
        int u = (t >= o) ? sh[t - o] : 0;
        __syncthreads();
        sh[t] += u;
        __syncthreads();
    }
    if (t < nb) bsum[t] = sh[t] - v;
}

__global__ __launch_bounds__(256) void k_scan_c(int* __restrict__ rowptr,
                                                int* __restrict__ cursor,
                                                const int* __restrict__ bsum,
                                                int N, int Etot) {
    const int i = blockIdx.x * 256 + threadIdx.x;
    if (i < N) {
        int v = rowptr[i] + bsum[blockIdx.x];
        rowptr[i] = v;
        cursor[i] = v;
    }
    if (i == 0) rowptr[N] = Etot;
}

// ---------------------------------------------------------------- CSR build: scatter src ids (+self-loops)
__global__ void k_fill(const int* __restrict__ ei, int* __restrict__ cursor,
                       int* __restrict__ col, int E, int N) {
    int g = blockIdx.x * blockDim.x + threadIdx.x;
    if (g >= E + N) return;
    int s, d;
    if (g < E) { s = ei[g]; d = ei[E + g]; } else { s = d = g - E; }
    int pos = atomicAdd(&cursor[d], 1);
    col[pos] = s;
}

// ---------------------------------------------------------------- prep: BN(x) -> bf16 A[N][128]; W1^T -> bf16 Wt[256][128]
__global__ __launch_bounds__(256) void k_prep(
    const float* __restrict__ x,
    const float* __restrict__ ing, const float* __restrict__ inb,
    const float* __restrict__ inm, const float* __restrict__ inv,
    const float* __restrict__ W1,
    unsigned short* __restrict__ A, unsigned short* __restrict__ Wt, int N)
{
    int g = blockIdx.x * blockDim.x + threadIdx.x;
    int totA = N * (DIN / 4);
    if (g < totA) {
        int n = g >> 5, k4 = (g & 31) * 4;
        float4 xv = *(const float4*)(x + (size_t)n * DIN + k4);
        float4 gm = *(const float4*)(ing + k4);
        float4 bb = *(const float4*)(inb + k4);
        float4 mm = *(const float4*)(inm + k4);
        float4 vv = *(const float4*)(inv + k4);
        ushort4 o;
        o.x = f2us((xv.x - mm.x) * rsqrtf(vv.x + EPS) * gm.x + bb.x);
        o.y = f2us((xv.y - mm.y) * rsqrtf(vv.y + EPS) * gm.y + bb.y);
        o.z = f2us((xv.z - mm.z) * rsqrtf(vv.z + EPS) * gm.z + bb.z);
        o.w = f2us((xv.w - mm.w) * rsqrtf(vv.w + EPS) * gm.w + bb.w);
        *(ushort4*)(A + (size_t)n * DIN + k4) = o;
    }
    if (g < 256 * DIN) {  // Wt[n][k] = W1[k][n]
        int n = g >> 7, k = g & 127;
        Wt[g] = f2us(W1[(size_t)k * 256 + n]);
    }
}

// ---------------------------------------------------------------- layer-1 GEMM via MFMA bf16 16x16x32
// block: 32 rows x 256 cols; 4 waves, wave wv owns cols wv*64..+64 (= head wv)
__global__ __launch_bounds__(256) void k_gemm1(
    const unsigned short* __restrict__ A,   // [N][128] bf16
    const unsigned short* __restrict__ Wt,  // [256][128] bf16
    const float* __restrict__ as_, const float* __restrict__ ad_, // [256]
    __hip_bfloat16* __restrict__ h, float* __restrict__ asrc, float* __restrict__ adst, int N)
{
    __shared__ float Csh[GM][260];          // stride 260: <=2-way banks on C writes
    const int t = threadIdx.x;
    const int lane = t & 63, wv = t >> 6;
    const int qm = lane & 15, qd = lane >> 4;
    const int base = blockIdx.x * GM;

    // a-frags [rt][ks]: A[base+rt*16+qm][ks*32 + qd*8 .. +8]  (16B global loads, L2)
    short8 afr[2][4];
    #pragma unroll
    for (int rt = 0; rt < 2; ++rt) {
        int node = base + rt * 16 + qm;
        if (node >= N) node = N - 1;        // safe clamp; epilogue skips rows >= N
        const unsigned short* ap = A + (size_t)node * DIN + qd * 8;
        #pragma unroll
        for (int ks = 0; ks < 4; ++ks)
            afr[rt][ks] = *(const short8*)(ap + ks * 32);
    }

    const int n0 = wv * 64;
    f32x4 acc[2][4];
    #pragma unroll
    for (int rt = 0; rt < 2; ++rt)
        #pragma unroll
        for (int ct = 0; ct < 4; ++ct)
            acc[rt][ct] = (f32x4){0.f, 0.f, 0.f, 0.f};

    #pragma unroll
    for (int ct = 0; ct < 4; ++ct) {
        const unsigned short* bp = Wt + (size_t)(n0 + ct * 16 + qm) * DIN + qd * 8;
        #pragma unroll
        for (int ks = 0; ks < 4; ++ks) {
            short8 bfr = *(const short8*)(bp + ks * 32);
            acc[0][ct] = __builtin_amdgcn_mfma_f32_16x16x32_bf16(afr[0][ks], bfr, acc[0][ct], 0, 0, 0);
            acc[1][ct] = __builtin_amdgcn_mfma_f32_16x16x32_bf16(afr[1][ks], bfr, acc[1][ct], 0, 0, 0);
        }
    }

    // C/D layout: col = n0+ct*16+qm, row = rt*16 + qd*4 + rg   [verified m89/m91]
    #pragma unroll
    for (int rt = 0; rt < 2; ++rt)
        #pragma unroll
        for (int ct = 0; ct < 4; ++ct)
            #pragma unroll
            for (int rg = 0; rg < 4; ++rg)
                Csh[rt * 16 + qd * 4 + rg][n0 + ct * 16 + qm] = acc[rt][ct][rg];
    __syncthreads();

    // epilogue: thread t <-> original col t (head = wv, channel = lane)
    const float asv = as_[t], adv = ad_[t];
    const int hcol = ((t & 3) << 6) | (t >> 2);   // h[n][t] <- C[n][(t&3)*64 + (t>>2)]
    for (int r = 0; r < GM; ++r) {
        int node = base + r;
        if (node >= N) break;
        h[(size_t)node * 256 + t] = __float2bfloat16(Csh[r][hcol]);
        float val = Csh[r][t];
        float vs = val * asv, vd = val * adv;
        #pragma unroll
        for (int o = 32; o > 0; o >>= 1) {
            vs += __shfl_down(vs, o, 64);
            vd += __shfl_down(vd, o, 64);
        }
        if (lane == 0) {
            asrc[node * NH + wv] = vs;
            adst[node * NH + wv] = vd;
        }
    }
}

// ---------------------------------------------------------------- layer-2 GEMM (unchanged VALU path)
__global__ __launch_bounds__(256) void k_gemm2(
    const float* __restrict__ outacc,
    const float* __restrict__ b1,
    const float* __restrict__ bg, const float* __restrict__ bb,
    const float* __restrict__ bm, const float* __restrict__ bv,
    const float* __restrict__ W,      // [64,256]
    const float* __restrict__ as_, const float* __restrict__ ad_,
    __hip_bfloat16* __restrict__ h, float* __restrict__ asrc, float* __restrict__ adst, int N)
{
    __shared__ float xs[ROWS][DHID];
    __shared__ __hip_bfloat16 hsh[ROWS][256];
    const int t = threadIdx.x;
    const int base = blockIdx.x * ROWS;

    #pragma unroll
    for (int j = 0; j < ROWS * DHID / 256; ++j) {
        int idx = t + j * 256;
        int r = idx >> 6, c = idx & 63;
        int node = base + r;
        float val = 0.f;
        if (node < N) {
            float raw = outacc[(size_t)node * DHID + c] + b1[c];
            float bnv = (raw - bm[c]) * rsqrtf(bv[c] + EPS) * bg[c] + bb[c];
            val = fmaxf(bnv, 0.f);
        }
        xs[r][c] = val;
    }
    __syncthreads();

    float acc[ROWS];
    #pragma unroll
    for (int r = 0; r < ROWS; ++r) acc[r] = 0.f;
    for (int k = 0; k < DHID; ++k) {
        float w = W[k * 256 + t];
        #pragma unroll
        for (int r = 0; r < ROWS; ++r) acc[r] += xs[r][k] * w;
    }

    const float asv = as_[t], adv = ad_[t];
    const int head = t >> 6, lane = t & 63;
    for (int r = 0; r < ROWS; ++r) {
        int node = base + r;
        if (node >= N) break;
        hsh[r][lane * 4 + head] = __float2bfloat16(acc[r]);
        float vs = acc[r] * asv, vd = acc[r] * adv;
        #pragma unroll
        for (int o = 32; o > 0; o >>= 1) {
            vs += __shfl_down(vs, o, 64);
            vd += __shfl_down(vd, o, 64);
        }
        if (lane == 0) {
            asrc[node * NH + head] = vs;
            adst[node * NH + head] = vd;
        }
    }
    __syncthreads();
    for (int r = 0; r < ROWS; ++r) {
        int node = base + r;
        if (node >= N) break;
        h[(size_t)node * 256 + t] = hsh[r][t];
    }
}

// ---------------------------------------------------------------- pull-style GAT aggregation (unchanged)
__global__ __launch_bounds__(256) void k_agg(
    const int* __restrict__ rowptr, const int* __restrict__ col,
    const float* __restrict__ asrc, const float* __restrict__ adst,
    const __hip_bfloat16* __restrict__ h, float* __restrict__ outacc, int N)
{
    __shared__ float4 exs[4][CAP];
    __shared__ int    cols[4][CAP];
    const int lane = threadIdx.x & 63;
    const int wv   = threadIdx.x >> 6;
    const int d = (blockIdx.x << 2) + wv;
    if (d >= N) return;
    const int r0  = rowptr[d];
    const int deg = rowptr[d + 1] - r0;

    const float4 ad4 = ((const float4*)adst)[d];
    const float4* __restrict__ as4 = (const float4*)asrc;

    float mx0 = -1e30f, mx1 = -1e30f, mx2 = -1e30f, mx3 = -1e30f;
    for (int j = lane; j < deg; j += 64) {
        int s = col[r0 + j];
        float4 a = as4[s];
        float a0 = lrelu(a.x + ad4.x), a1 = lrelu(a.y + ad4.y);
        float a2 = lrelu(a.z + ad4.z), a3 = lrelu(a.w + ad4.w);
        if (j < CAP) { cols[wv][j] = s; exs[wv][j] = make_float4(a0, a1, a2, a3); }
        mx0 = fmaxf(mx0, a0); mx1 = fmaxf(mx1, a1);
        mx2 = fmaxf(mx2, a2); mx3 = fmaxf(mx3, a3);
    }
    #pragma unroll
    for (int o = 1; o < 64; o <<= 1) {
        mx0 = fmaxf(mx0, __shfl_xor(mx0, o, 64));
        mx1 = fmaxf(mx1, __shfl_xor(mx1, o, 64));
        mx2 = fmaxf(mx2, __shfl_xor(mx2, o, 64));
        mx3 = fmaxf(mx3, __shfl_xor(mx3, o, 64));
    }

    float sm0 = 0.f, sm1 = 0.f, sm2 = 0.f, sm3 = 0.f;
    for (int j = lane; j < deg; j += 64) {
        float a0, a1, a2, a3;
        if (j < CAP) { float4 a = exs[wv][j]; a0 = a.x; a1 = a.y; a2 = a.z; a3 = a.w; }
        else {
            int s = col[r0 + j];
            float4 a = as4[s];
            a0 = lrelu(a.x + ad4.x); a1 = lrelu(a.y + ad4.y);
            a2 = lrelu(a.z + ad4.z); a3 = lrelu(a.w + ad4.w);
        }
        float e0 = __expf(a0 - mx0), e1 = __expf(a1 - mx1);
        float e2 = __expf(a2 - mx2), e3 = __expf(a3 - mx3);
        if (j < CAP) exs[wv][j] = make_float4(e0, e1, e2, e3);
        sm0 += e0; sm1 += e1; sm2 += e2; sm3 += e3;
    }
    #pragma unroll
    for (int o = 1; o < 64; o <<= 1) {
        sm0 += __shfl_xor(sm0, o, 64);
        sm1 += __shfl_xor(sm1, o, 64);
        sm2 += __shfl_xor(sm2, o, 64);
        sm3 += __shfl_xor(sm3, o, 64);
    }
    const float i0 = 0.25f / sm0, i1 = 0.25f / sm1, i2 = 0.25f / sm2, i3 = 0.25f / sm3;

    const ushort4* __restrict__ hv = (const ushort4*)h;
    float acc = 0.f;
    for (int j = 0; j < deg; ++j) {
        int s; float w0, w1, w2, w3;
        if (j < CAP) {
            s = cols[wv][j];
            float4 w = exs[wv][j];
            w0 = w.x * i0; w1 = w.y * i1; w2 = w.z * i2; w3 = w.w * i3;
        } else {
            s = col[r0 + j];
            float4 a = as4[s];
            w0 = __expf(lrelu(a.x + ad4.x) - mx0) * i0;
            w1 = __expf(lrelu(a.y + ad4.y) - mx1) * i1;
            w2 = __expf(lrelu(a.z + ad4.z) - mx2) * i2;
            w3 = __expf(lrelu(a.w + ad4.w) - mx3) * i3;
        }
        ushort4 v = hv[(size_t)s * 64 + lane];
        acc += w0 * us2f(v.x) + w1 * us2f(v.y) + w2 * us2f(v.z) + w3 * us2f(v.w);
    }
    outacc[(size_t)d * 64 + lane] = acc;
}

// ---------------------------------------------------------------- pool (unchanged)
__global__ __launch_bounds__(256) void k_pool(
    const float* __restrict__ outacc,
    const float* __restrict__ b2_,
    const float* __restrict__ bg, const float* __restrict__ bb,
    const float* __restrict__ bm, const float* __restrict__ bv,
    const int* __restrict__ batch,
    float* __restrict__ pool, float* __restrict__ cnt, int N)
{
    const int lane = threadIdx.x & 63;
    const int wave = threadIdx.x >> 6;
    const int base = blockIdx.x * PNODES;
    int end = base + PNODES; if (end > N) end = N;

    const float scale = bg[lane] * rsqrtf(bv[lane] + EPS);
    const float shift = (b2_[lane] - bm[lane]) * scale + bb[lane];

    float acc = 0.f;
    int cur = -1, cl = 0;
    for (int n = base + wave; n < end; n += 4) {
        int gr = batch[n];
        if (gr != cur) {
            if (cur >= 0) {
                atomicAdd(&pool[cur * 64 + lane], acc);
                if (lane == 0) atomicAdd(&cnt[cur], (float)cl);
            }
            cur = gr; acc = 0.f; cl = 0;
        }
        float v = fmaxf(outacc[(size_t)n * 64 + lane] * scale + shift, 0.f);
        acc += v; ++cl;
    }
    if (cur >= 0) {
        atomicAdd(&pool[cur * 64 + lane], acc);
        if (lane == 0) atomicAdd(&cnt[cur], (float)cl);
    }
}

// ---------------------------------------------------------------- head (unchanged)
__global__ void k_head(const float* __restrict__ pool, const float* __restrict__ cnt,
                       const float* __restrict__ fc1w, const float* __restrict__ fc1b,
                       const float* __restrict__ fc2w, const float* __restrict__ fc2b,
                       float* __restrict__ out)
{
    int g = blockIdx.x;
    int t = threadIdx.x;  // 64 threads
    __shared__ float emb[64];
    __shared__ float z1[32];
    float c = fmaxf(cnt[g], 1.0f);
    emb[t] = pool[g * 64 + t] / c;
    __syncthreads();
    if (t < 32) {
        float s = fc1b[t];
        for (int k = 0; k < 64; ++k) s += emb[k] * fc1w[k * 32 + t];
        z1[t] = fmaxf(s, 0.f);
    }
    __syncthreads();
    if (t < 32) {
        float o = fc2b[t];
        for (int j = 0; j < 32; ++j) o += z1[j] * fc2w[j * 32 + t];
        out[g * 32 + t] = o;
    }
}

// ---------------------------------------------------------------- launch
extern "C" void kernel_launch(void* const* d_in, const int* in_sizes, int n_in,
                              void* d_out, int out_size, void* d_ws, size_t ws_size,
                              hipStream_t stream)
{
    const float* x    = (const float*)d_in[0];
    const int*   ei   = (const int*)d_in[1];
    const int*   batch= (const int*)d_in[2];
    const float* ing  = (const float*)d_in[3];
    const float* inb  = (const float*)d_in[4];
    const float* inm  = (const float*)d_in[5];
    const float* inv  = (const float*)d_in[6];
    const float* W1   = (const float*)d_in[7];
    const float* as1  = (const float*)d_in[8];
    const float* ad1  = (const float*)d_in[9];
    const float* b1   = (const float*)d_in[10];
    const float* bn1g = (const float*)d_in[11];
    const float* bn1b = (const float*)d_in[12];
    const float* bn1m = (const float*)d_in[13];
    const float* bn1v = (const float*)d_in[14];
    const float* W2   = (const float*)d_in[15];
    const float* as2  = (const float*)d_in[16];
    const float* ad2  = (const float*)d_in[17];
    const float* b2   = (const float*)d_in[18];
    const float* bn2g = (const float*)d_in[19];
    const float* bn2b = (const float*)d_in[20];
    const float* bn2m = (const float*)d_in[21];
    const float* bn2v = (const float*)d_in[22];
    const float* fc1w = (const float*)d_in[23];
    const float* fc1b = (const float*)d_in[24];
    const float* fc2w = (const float*)d_in[25];
    const float* fc2b = (const float*)d_in[26];

    const int N = in_sizes[0] / DIN;
    const int E = in_sizes[1] / 2;
    const int G = out_size / DOUT;
    const int Etot = E + N;

    // workspace layout — ~44.7 MB (A bf16 aliases outacc storage)
    __hip_bfloat16* h = (__hip_bfloat16*)d_ws;            // N*256 bf16 (transposed [n][c][hd])
    float* asrc   = (float*)(h + (size_t)N * 256);        // N*4
    float* adst   = asrc + (size_t)N * NH;                // N*4
    unsigned short* Wt = (unsigned short*)(adst + (size_t)N * NH); // 256*128 bf16 (64 KB, 16B-aligned)
    float* outacc = (float*)(Wt + 256 * DIN);             // N*64 f32
    unsigned short* A = (unsigned short*)outacc;          // alias: N*128 bf16, dead after k_gemm1
    int*   deg    = (int*)(outacc + (size_t)N * DHID);    // N
    int*   rowptr = deg + N;                              // N+1
    int*   cursor = rowptr + N + 1;                       // N
    int*   col    = cursor + N;                           // E+N
    float* pool   = (float*)(col + Etot);                 // G*64
    float* cnt    = pool + (size_t)G * DHID;              // G
    int*   bsum   = (int*)(cnt + G);                      // ceil(N/256) <= 256

    const int npool = G * DHID + G;
    const int nScanBlk = (N + 255) / 256;
    dim3 b256(256);

    // ---- CSR build (shared by both layers) + zero pool/cnt
    k_init0<<<(N + 255) / 256, b256, 0, stream>>>(deg, pool, N, npool);
    k_hist<<<(E + 255) / 256, b256, 0, stream>>>(ei, deg, E);
    k_scan_a<<<nScanBlk, b256, 0, stream>>>(deg, rowptr, bsum, N);
    k_scan_b<<<1, b256, 0, stream>>>(bsum, nScanBlk);
    k_scan_c<<<nScanBlk, b256, 0, stream>>>(rowptr, cursor, bsum, N, Etot);
    k_fill<<<(Etot + 255) / 256, b256, 0, stream>>>(ei, cursor, col, E, N);

    // ---- prep (BN+cast x, transpose W1)
    const int prepThreads = N * (DIN / 4);
    k_prep<<<(prepThreads + 255) / 256, b256, 0, stream>>>(x, ing, inb, inm, inv, W1, A, Wt, N);

    // ---- layer 1 (MFMA)
    k_gemm1<<<(N + GM - 1) / GM, b256, 0, stream>>>(A, Wt, as1, ad1, h, asrc, adst, N);
    k_agg<<<(N + 3) / 4, b256, 0, stream>>>(rowptr, col, asrc, adst, h, outacc, N);

    // ---- layer 2
    k_gemm2<<<(N + ROWS - 1) / ROWS, b256, 0, stream>>>(outacc, b1, bn1g, bn1b, bn1m, bn1v,
                                                        W2, as2, ad2, h, asrc, adst, N);
    k_agg<<<(N + 3) / 4, b256, 0, stream>>>(rowptr, col, asrc, adst, h, outacc, N);

    // ---- pool + head
    k_pool<<<(N + PNODES - 1) / PNODES, b256, 0, stream>>>(outacc, b2, bn2g, bn2b, bn2m, bn2v,
                                                           batch, pool, cnt, N);
    k_head<<<G, 64, 0, stream>>>(pool, cnt, fc1w, fc1b, fc2w, fc2b, (float*)d_out);
}

// Round 10
// 473.248 us; speedup vs baseline: 2.3772x; 1.0287x over previous
//
#include <hip/hip_runtime.h>
#include <hip/hip_bf16.h>

#define EPS   1e-5f
#define NH    4      // heads
#define DIN   128
#define DHID  64
#define DOUT  32
#define PNODES 256   // nodes per k_pool block
#define CAP   128    // per-wave LDS edge capacity in k_agg
#define GM    32     // rows per MFMA gemm block

typedef __attribute__((ext_vector_type(8))) short short8;   // 8 bf16 (4 VGPRs)
typedef __attribute__((ext_vector_type(4))) float f32x4;    // MFMA accumulator

__device__ __forceinline__ float b2f(__hip_bfloat16 v) { return __bfloat162float(v); }
__device__ __forceinline__ float us2f(unsigned short u) {   // raw bf16 bits -> f32
    return __uint_as_float((unsigned)u << 16);
}
__device__ __forceinline__ unsigned short f2us(float v) {   // f32 -> bf16 bits (RN)
    __hip_bfloat16 hb = __float2bfloat16(v);
    return *(unsigned short*)&hb;
}
__device__ __forceinline__ float lrelu(float a) { return (a >= 0.f) ? a : 0.2f * a; }

// ---------------------------------------------------------------- init: deg=1 (self-loop), zero pool/cnt
__global__ void k_init0(int* __restrict__ deg, float* __restrict__ pool, int N, int npool) {
    int g = blockIdx.x * blockDim.x + threadIdx.x;
    if (g < N) deg[g] = 1;
    if (g < npool) pool[g] = 0.f;
}

// ---------------------------------------------------------------- CSR build: histogram of dst
__global__ void k_hist(const int* __restrict__ ei, int* __restrict__ deg, int E) {
    int e = blockIdx.x * blockDim.x + threadIdx.x;
    if (e < E) atomicAdd(&deg[ei[E + e]], 1);
}

// ---------------------------------------------------------------- 3-phase parallel exclusive scan
__global__ __launch_bounds__(256) void k_scan_a(const int* __restrict__ deg,
                                                int* __restrict__ rowptr,
                                                int* __restrict__ bsum, int N) {
    __shared__ int sh[256];
    const int t = threadIdx.x;
    const int i = blockIdx.x * 256 + t;
    int v = (i < N) ? deg[i] : 0;
    sh[t] = v;
    __syncthreads();
    #pragma unroll
    for (int o = 1; o < 256; o <<= 1) {
        int u = (t >= o) ? sh[t - o] : 0;
        __syncthreads();
        sh[t] += u;
        __syncthreads();
    }
    if (i < N) rowptr[i] = sh[t] - v;
    if (t == 255) bsum[blockIdx.x] = sh[255];
}

__global__ __launch_bounds__(256) void k_scan_b(int* __restrict__ bsum, int nb) {
    __shared__ int sh[256];
    const int t = threadIdx.x;
    int v = (t < nb) ? bsum[t] : 0;
    sh[t] = v;
    __syncthreads();
    #pragma unroll
    for (int o = 1; o < 256; o <<= 1) {
        int u = (t >= o) ? sh[t - o] : 0;
        __syncthreads();
        sh[t] += u;
        __syncthreads();
    }
    if (t < nb) bsum[t] = sh[t] - v;
}

__global__ __launch_bounds__(256) void k_scan_c(int* __restrict__ rowptr,
                                                int* __restrict__ cursor,
                                                const int* __restrict__ bsum,
                                                int N, int Etot) {
    const int i = blockIdx.x * 256 + threadIdx.x;
    if (i < N) {
        int v = rowptr[i] + bsum[blockIdx.x];
        rowptr[i] = v;
        cursor[i] = v;
    }
    if (i == 0) rowptr[N] = Etot;
}

// ---------------------------------------------------------------- CSR build: scatter src ids (+self-loops)
__global__ void k_fill(const int* __restrict__ ei, int* __restrict__ cursor,
                       int* __restrict__ col, int E, int N) {
    int g = blockIdx.x * blockDim.x + threadIdx.x;
    if (g >= E + N) return;
    int s, d;
    if (g < E) { s = ei[g]; d = ei[E + g]; } else { s = d = g - E; }
    int pos = atomicAdd(&cursor[d], 1);
    col[pos] = s;
}

// ---------------------------------------------------------------- prep:
// BN(x)->bf16 A[N][128]; W1^T->Wt[256][128]; W2^T->Wt2[256][64]; BN1 scale/shift vectors
__global__ __launch_bounds__(256) void k_prep(
    const float* __restrict__ x,
    const float* __restrict__ ing, const float* __restrict__ inb,
    const float* __restrict__ inm, const float* __restrict__ inv,
    const float* __restrict__ W1, const float* __restrict__ W2,
    const float* __restrict__ b1,
    const float* __restrict__ bn1g, const float* __restrict__ bn1b,
    const float* __restrict__ bn1m, const float* __restrict__ bn1v,
    unsigned short* __restrict__ A, unsigned short* __restrict__ Wt,
    unsigned short* __restrict__ Wt2,
    float* __restrict__ scl1, float* __restrict__ shf1, int N)
{
    int g = blockIdx.x * blockDim.x + threadIdx.x;
    int totA = N * (DIN / 4);
    if (g < totA) {
        int n = g >> 5, k4 = (g & 31) * 4;
        float4 xv = *(const float4*)(x + (size_t)n * DIN + k4);
        float4 gm = *(const float4*)(ing + k4);
        float4 bb = *(const float4*)(inb + k4);
        float4 mm = *(const float4*)(inm + k4);
        float4 vv = *(const float4*)(inv + k4);
        ushort4 o;
        o.x = f2us((xv.x - mm.x) * rsqrtf(vv.x + EPS) * gm.x + bb.x);
        o.y = f2us((xv.y - mm.y) * rsqrtf(vv.y + EPS) * gm.y + bb.y);
        o.z = f2us((xv.z - mm.z) * rsqrtf(vv.z + EPS) * gm.z + bb.z);
        o.w = f2us((xv.w - mm.w) * rsqrtf(vv.w + EPS) * gm.w + bb.w);
        *(ushort4*)(A + (size_t)n * DIN + k4) = o;
    }
    if (g < 256 * DIN) {   // Wt[n][k] = W1[k][n]
        int n = g >> 7, k = g & 127;
        Wt[g] = f2us(W1[(size_t)k * 256 + n]);
    }
    if (g < 256 * DHID) {  // Wt2[n][k] = W2[k][n]
        int n = g >> 6, k = g & 63;
        Wt2[g] = f2us(W2[(size_t)k * 256 + n]);
    }
    if (g < DHID) {        // fold b1 + BN1 into scale/shift
        float sc = bn1g[g] * rsqrtf(bn1v[g] + EPS);
        scl1[g] = sc;
        shf1[g] = (b1[g] - bn1m[g]) * sc + bn1b[g];
    }
}

// ---------------------------------------------------------------- layer-1 GEMM via MFMA bf16 16x16x32
__global__ __launch_bounds__(256) void k_gemm1(
    const unsigned short* __restrict__ A,   // [N][128] bf16
    const unsigned short* __restrict__ Wt,  // [256][128] bf16
    const float* __restrict__ as_, const float* __restrict__ ad_, // [256]
    __hip_bfloat16* __restrict__ h, float* __restrict__ asrc, float* __restrict__ adst, int N)
{
    __shared__ float Csh[GM][260];
    const int t = threadIdx.x;
    const int lane = t & 63, wv = t >> 6;
    const int qm = lane & 15, qd = lane >> 4;
    const int base = blockIdx.x * GM;

    short8 afr[2][4];
    #pragma unroll
    for (int rt = 0; rt < 2; ++rt) {
        int node = base + rt * 16 + qm;
        if (node >= N) node = N - 1;
        const unsigned short* ap = A + (size_t)node * DIN + qd * 8;
        #pragma unroll
        for (int ks = 0; ks < 4; ++ks)
            afr[rt][ks] = *(const short8*)(ap + ks * 32);
    }

    const int n0 = wv * 64;
    f32x4 acc[2][4];
    #pragma unroll
    for (int rt = 0; rt < 2; ++rt)
        #pragma unroll
        for (int ct = 0; ct < 4; ++ct)
            acc[rt][ct] = (f32x4){0.f, 0.f, 0.f, 0.f};

    #pragma unroll
    for (int ct = 0; ct < 4; ++ct) {
        const unsigned short* bp = Wt + (size_t)(n0 + ct * 16 + qm) * DIN + qd * 8;
        #pragma unroll
        for (int ks = 0; ks < 4; ++ks) {
            short8 bfr = *(const short8*)(bp + ks * 32);
            acc[0][ct] = __builtin_amdgcn_mfma_f32_16x16x32_bf16(afr[0][ks], bfr, acc[0][ct], 0, 0, 0);
            acc[1][ct] = __builtin_amdgcn_mfma_f32_16x16x32_bf16(afr[1][ks], bfr, acc[1][ct], 0, 0, 0);
        }
    }

    #pragma unroll
    for (int rt = 0; rt < 2; ++rt)
        #pragma unroll
        for (int ct = 0; ct < 4; ++ct)
            #pragma unroll
            for (int rg = 0; rg < 4; ++rg)
                Csh[rt * 16 + qd * 4 + rg][n0 + ct * 16 + qm] = acc[rt][ct][rg];
    __syncthreads();

    const float asv = as_[t], adv = ad_[t];
    const int hcol = ((t & 3) << 6) | (t >> 2);
    for (int r = 0; r < GM; ++r) {
        int node = base + r;
        if (node >= N) break;
        h[(size_t)node * 256 + t] = __float2bfloat16(Csh[r][hcol]);
        float val = Csh[r][t];
        float vs = val * asv, vd = val * adv;
        #pragma unroll
        for (int o = 32; o > 0; o >>= 1) {
            vs += __shfl_down(vs, o, 64);
            vd += __shfl_down(vd, o, 64);
        }
        if (lane == 0) {
            asrc[node * NH + wv] = vs;
            adst[node * NH + wv] = vd;
        }
    }
}

// ---------------------------------------------------------------- layer-2 GEMM via MFMA (K=64)
__global__ __launch_bounds__(256) void k_gemm2(
    const unsigned short* __restrict__ A2,  // [N][64] bf16 (BN1+ReLU already applied)
    const unsigned short* __restrict__ Wt2, // [256][64] bf16
    const float* __restrict__ as_, const float* __restrict__ ad_,
    __hip_bfloat16* __restrict__ h, float* __restrict__ asrc, float* __restrict__ adst, int N)
{
    __shared__ float Csh[GM][260];
    const int t = threadIdx.x;
    const int lane = t & 63, wv = t >> 6;
    const int qm = lane & 15, qd = lane >> 4;
    const int base = blockIdx.x * GM;

    short8 afr[2][2];
    #pragma unroll
    for (int rt = 0; rt < 2; ++rt) {
        int node = base + rt * 16 + qm;
        if (node >= N) node = N - 1;
        const unsigned short* ap = A2 + (size_t)node * DHID + qd * 8;
        #pragma unroll
        for (int ks = 0; ks < 2; ++ks)
            afr[rt][ks] = *(const short8*)(ap + ks * 32);
    }

    const int n0 = wv * 64;
    f32x4 acc[2][4];
    #pragma unroll
    for (int rt = 0; rt < 2; ++rt)
        #pragma unroll
        for (int ct = 0; ct < 4; ++ct)
            acc[rt][ct] = (f32x4){0.f, 0.f, 0.f, 0.f};

    #pragma unroll
    for (int ct = 0; ct < 4; ++ct) {
        const unsigned short* bp = Wt2 + (size_t)(n0 + ct * 16 + qm) * DHID + qd * 8;
        #pragma unroll
        for (int ks = 0; ks < 2; ++ks) {
            short8 bfr = *(const short8*)(bp + ks * 32);
            acc[0][ct] = __builtin_amdgcn_mfma_f32_16x16x32_bf16(afr[0][ks], bfr, acc[0][ct], 0, 0, 0);
            acc[1][ct] = __builtin_amdgcn_mfma_f32_16x16x32_bf16(afr[1][ks], bfr, acc[1][ct], 0, 0, 0);
        }
    }

    #pragma unroll
    for (int rt = 0; rt < 2; ++rt)
        #pragma unroll
        for (int ct = 0; ct < 4; ++ct)
            #pragma unroll
            for (int rg = 0; rg < 4; ++rg)
                Csh[rt * 16 + qd * 4 + rg][n0 + ct * 16 + qm] = acc[rt][ct][rg];
    __syncthreads();

    const float asv = as_[t], adv = ad_[t];
    const int hcol = ((t & 3) << 6) | (t >> 2);
    for (int r = 0; r < GM; ++r) {
        int node = base + r;
        if (node >= N) break;
        h[(size_t)node * 256 + t] = __float2bfloat16(Csh[r][hcol]);
        float val = Csh[r][t];
        float vs = val * asv, vd = val * adv;
        #pragma unroll
        for (int o = 32; o > 0; o >>= 1) {
            vs += __shfl_down(vs, o, 64);
            vd += __shfl_down(vd, o, 64);
        }
        if (lane == 0) {
            asrc[node * NH + wv] = vs;
            adst[node * NH + wv] = vd;
        }
    }
}

// ---------------------------------------------------------------- pull-style GAT aggregation
// mode 1: write bf16 relu(acc*scl[c]+shf[c]) (feeds MFMA gemm2); mode 0: raw f32 (feeds pool)
__global__ __launch_bounds__(256) void k_agg(
    const int* __restrict__ rowptr, const int* __restrict__ col,
    const float* __restrict__ asrc, const float* __restrict__ adst,
    const __hip_bfloat16* __restrict__ h,
    float* __restrict__ outf, unsigned short* __restrict__ outb,
    const float* __restrict__ scl, const float* __restrict__ shf,
    int mode, int N)
{
    __shared__ float4 exs[4][CAP];
    __shared__ int    cols[4][CAP];
    const int lane = threadIdx.x & 63;
    const int wv   = threadIdx.x >> 6;
    const int d = (blockIdx.x << 2) + wv;
    if (d >= N) return;
    const int r0  = rowptr[d];
    const int deg = rowptr[d + 1] - r0;

    const float4 ad4 = ((const float4*)adst)[d];
    const float4* __restrict__ as4 = (const float4*)asrc;

    float mx0 = -1e30f, mx1 = -1e30f, mx2 = -1e30f, mx3 = -1e30f;
    for (int j = lane; j < deg; j += 64) {
        int s = col[r0 + j];
        float4 a = as4[s];
        float a0 = lrelu(a.x + ad4.x), a1 = lrelu(a.y + ad4.y);
        float a2 = lrelu(a.z + ad4.z), a3 = lrelu(a.w + ad4.w);
        if (j < CAP) { cols[wv][j] = s; exs[wv][j] = make_float4(a0, a1, a2, a3); }
        mx0 = fmaxf(mx0, a0); mx1 = fmaxf(mx1, a1);
        mx2 = fmaxf(mx2, a2); mx3 = fmaxf(mx3, a3);
    }
    #pragma unroll
    for (int o = 1; o < 64; o <<= 1) {
        mx0 = fmaxf(mx0, __shfl_xor(mx0, o, 64));
        mx1 = fmaxf(mx1, __shfl_xor(mx1, o, 64));
        mx2 = fmaxf(mx2, __shfl_xor(mx2, o, 64));
        mx3 = fmaxf(mx3, __shfl_xor(mx3, o, 64));
    }

    float sm0 = 0.f, sm1 = 0.f, sm2 = 0.f, sm3 = 0.f;
    for (int j = lane; j < deg; j += 64) {
        float a0, a1, a2, a3;
        if (j < CAP) { float4 a = exs[wv][j]; a0 = a.x; a1 = a.y; a2 = a.z; a3 = a.w; }
        else {
            int s = col[r0 + j];
            float4 a = as4[s];
            a0 = lrelu(a.x + ad4.x); a1 = lrelu(a.y + ad4.y);
            a2 = lrelu(a.z + ad4.z); a3 = lrelu(a.w + ad4.w);
        }
        float e0 = __expf(a0 - mx0), e1 = __expf(a1 - mx1);
        float e2 = __expf(a2 - mx2), e3 = __expf(a3 - mx3);
        if (j < CAP) exs[wv][j] = make_float4(e0, e1, e2, e3);
        sm0 += e0; sm1 += e1; sm2 += e2; sm3 += e3;
    }
    #pragma unroll
    for (int o = 1; o < 64; o <<= 1) {
        sm0 += __shfl_xor(sm0, o, 64);
        sm1 += __shfl_xor(sm1, o, 64);
        sm2 += __shfl_xor(sm2, o, 64);
        sm3 += __shfl_xor(sm3, o, 64);
    }
    const float i0 = 0.25f / sm0, i1 = 0.25f / sm1, i2 = 0.25f / sm2, i3 = 0.25f / sm3;

    const ushort4* __restrict__ hv = (const ushort4*)h;
    float acc = 0.f;
    for (int j = 0; j < deg; ++j) {
        int s; float w0, w1, w2, w3;
        if (j < CAP) {
            s = cols[wv][j];
            float4 w = exs[wv][j];
            w0 = w.x * i0; w1 = w.y * i1; w2 = w.z * i2; w3 = w.w * i3;
        } else {
            s = col[r0 + j];
            float4 a = as4[s];
            w0 = __expf(lrelu(a.x + ad4.x) - mx0) * i0;
            w1 = __expf(lrelu(a.y + ad4.y) - mx1) * i1;
            w2 = __expf(lrelu(a.z + ad4.z) - mx2) * i2;
            w3 = __expf(lrelu(a.w + ad4.w) - mx3) * i3;
        }
        ushort4 v = hv[(size_t)s * 64 + lane];
        acc += w0 * us2f(v.x) + w1 * us2f(v.y) + w2 * us2f(v.z) + w3 * us2f(v.w);
    }
    if (mode) {
        float v = fmaxf(acc * scl[lane] + shf[lane], 0.f);
        outb[(size_t)d * 64 + lane] = f2us(v);
    } else {
        outf[(size_t)d * 64 + lane] = acc;
    }
}

// ---------------------------------------------------------------- pool (unchanged)
__global__ __launch_bounds__(256) void k_pool(
    const float* __restrict__ outacc,
    const float* __restrict__ b2_,
    const float* __restrict__ bg, const float* __restrict__ bb,
    const float* __restrict__ bm, const float* __restrict__ bv,
    const int* __restrict__ batch,
    float* __restrict__ pool, float* __restrict__ cnt, int N)
{
    const int lane = threadIdx.x & 63;
    const int wave = threadIdx.x >> 6;
    const int base = blockIdx.x * PNODES;
    int end = base + PNODES; if (end > N) end = N;

    const float scale = bg[lane] * rsqrtf(bv[lane] + EPS);
    const float shift = (b2_[lane] - bm[lane]) * scale + bb[lane];

    float acc = 0.f;
    int cur = -1, cl = 0;
    for (int n = base + wave; n < end; n += 4) {
        int gr = batch[n];
        if (gr != cur) {
            if (cur >= 0) {
                atomicAdd(&pool[cur * 64 + lane], acc);
                if (lane == 0) atomicAdd(&cnt[cur], (float)cl);
            }
            cur = gr; acc = 0.f; cl = 0;
        }
        float v = fmaxf(outacc[(size_t)n * 64 + lane] * scale + shift, 0.f);
        acc += v; ++cl;
    }
    if (cur >= 0) {
        atomicAdd(&pool[cur * 64 + lane], acc);
        if (lane == 0) atomicAdd(&cnt[cur], (float)cl);
    }
}

// ---------------------------------------------------------------- head (unchanged)
__global__ void k_head(const float* __restrict__ pool, const float* __restrict__ cnt,
                       const float* __restrict__ fc1w, const float* __restrict__ fc1b,
                       const float* __restrict__ fc2w, const float* __restrict__ fc2b,
                       float* __restrict__ out)
{
    int g = blockIdx.x;
    int t = threadIdx.x;  // 64 threads
    __shared__ float emb[64];
    __shared__ float z1[32];
    float c = fmaxf(cnt[g], 1.0f);
    emb[t] = pool[g * 64 + t] / c;
    __syncthreads();
    if (t < 32) {
        float s = fc1b[t];
        for (int k = 0; k < 64; ++k) s += emb[k] * fc1w[k * 32 + t];
        z1[t] = fmaxf(s, 0.f);
    }
    __syncthreads();
    if (t < 32) {
        float o = fc2b[t];
        for (int j = 0; j < 32; ++j) o += z1[j] * fc2w[j * 32 + t];
        out[g * 32 + t] = o;
    }
}

// ---------------------------------------------------------------- launch
extern "C" void kernel_launch(void* const* d_in, const int* in_sizes, int n_in,
                              void* d_out, int out_size, void* d_ws, size_t ws_size,
                              hipStream_t stream)
{
    const float* x    = (const float*)d_in[0];
    const int*   ei   = (const int*)d_in[1];
    const int*   batch= (const int*)d_in[2];
    const float* ing  = (const float*)d_in[3];
    const float* inb  = (const float*)d_in[4];
    const float* inm  = (const float*)d_in[5];
    const float* inv  = (const float*)d_in[6];
    const float* W1   = (const float*)d_in[7];
    const float* as1  = (const float*)d_in[8];
    const float* ad1  = (const float*)d_in[9];
    const float* b1   = (const float*)d_in[10];
    const float* bn1g = (const float*)d_in[11];
    const float* bn1b = (const float*)d_in[12];
    const float* bn1m = (const float*)d_in[13];
    const float* bn1v = (const float*)d_in[14];
    const float* W2   = (const float*)d_in[15];
    const float* as2  = (const float*)d_in[16];
    const float* ad2  = (const float*)d_in[17];
    const float* b2   = (const float*)d_in[18];
    const float* bn2g = (const float*)d_in[19];
    const float* bn2b = (const float*)d_in[20];
    const float* bn2m = (const float*)d_in[21];
    const float* bn2v = (const float*)d_in[22];
    const float* fc1w = (const float*)d_in[23];
    const float* fc1b = (const float*)d_in[24];
    const float* fc2w = (const float*)d_in[25];
    const float* fc2b = (const float*)d_in[26];

    const int N = in_sizes[0] / DIN;
    const int E = in_sizes[1] / 2;
    const int G = out_size / DOUT;
    const int Etot = E + N;

    // workspace layout — ~45 MB
    __hip_bfloat16* h = (__hip_bfloat16*)d_ws;            // N*256 bf16 (transposed [n][c][hd])
    float* asrc   = (float*)(h + (size_t)N * 256);        // N*4
    float* adst   = asrc + (size_t)N * NH;                // N*4
    unsigned short* Wt  = (unsigned short*)(adst + (size_t)N * NH); // 256*128 bf16
    unsigned short* Wt2 = Wt + 256 * DIN;                 // 256*64 bf16
    float* scl1   = (float*)(Wt2 + 256 * DHID);           // 64
    float* shf1   = scl1 + DHID;                          // 64
    float* outacc = shf1 + DHID;                          // N*64 f32
    unsigned short* A  = (unsigned short*)outacc;         // alias: N*128 bf16 (dead after gemm1)
    unsigned short* A2 = (unsigned short*)outacc;         // alias: N*64 bf16 (layer-1 agg out)
    int*   deg    = (int*)(outacc + (size_t)N * DHID);    // N
    int*   rowptr = deg + N;                              // N+1
    int*   cursor = rowptr + N + 1;                       // N
    int*   col    = cursor + N;                           // E+N
    float* pool   = (float*)(col + Etot);                 // G*64
    float* cnt    = pool + (size_t)G * DHID;              // G
    int*   bsum   = (int*)(cnt + G);                      // ceil(N/256) <= 256

    const int npool = G * DHID + G;
    const int nScanBlk = (N + 255) / 256;
    dim3 b256(256);

    // ---- CSR build (shared by both layers) + zero pool/cnt
    k_init0<<<(N + 255) / 256, b256, 0, stream>>>(deg, pool, N, npool);
    k_hist<<<(E + 255) / 256, b256, 0, stream>>>(ei, deg, E);
    k_scan_a<<<nScanBlk, b256, 0, stream>>>(deg, rowptr, bsum, N);
    k_scan_b<<<1, b256, 0, stream>>>(bsum, nScanBlk);
    k_scan_c<<<nScanBlk, b256, 0, stream>>>(rowptr, cursor, bsum, N, Etot);
    k_fill<<<(Etot + 255) / 256, b256, 0, stream>>>(ei, cursor, col, E, N);

    // ---- prep (BN+cast x, transpose W1/W2, BN1 fold)
    const int prepThreads = N * (DIN / 4);
    k_prep<<<(prepThreads + 255) / 256, b256, 0, stream>>>(
        x, ing, inb, inm, inv, W1, W2, b1, bn1g, bn1b, bn1m, bn1v,
        A, Wt, Wt2, scl1, shf1, N);

    // ---- layer 1 (MFMA) ; agg writes bf16 A2 with fused bias+BN1+ReLU
    k_gemm1<<<(N + GM - 1) / GM, b256, 0, stream>>>(A, Wt, as1, ad1, h, asrc, adst, N);
    k_agg<<<(N + 3) / 4, b256, 0, stream>>>(rowptr, col, asrc, adst, h,
                                            (float*)nullptr, A2, scl1, shf1, 1, N);

    // ---- layer 2 (MFMA) ; agg writes raw f32 for pool
    k_gemm2<<<(N + GM - 1) / GM, b256, 0, stream>>>(A2, Wt2, as2, ad2, h, asrc, adst, N);
    k_agg<<<(N + 3) / 4, b256, 0, stream>>>(rowptr, col, asrc, adst, h,
                                            outacc, (unsigned short*)nullptr,
                                            (const float*)nullptr, (const float*)nullptr, 0, N);

    // ---- pool + head
    k_pool<<<(N + PNODES - 1) / PNODES, b256, 0, stream>>>(outacc, b2, bn2g, bn2b, bn2m, bn2v,
                                                           batch, pool, cnt, N);
    k_head<<<G, 64, 0, stream>>>(pool, cnt, fc1w, fc1b, fc2w, fc2b, (float*)d_out);
}